// Round 17
// baseline (762.386 us; speedup 1.0000x reference)
//
#include <hip/hip_runtime.h>
#include <hip/hip_bf16.h>

#define NF 128
#define RBF 20

using short8 = __attribute__((ext_vector_type(8))) short;
using half8  = __attribute__((ext_vector_type(8))) _Float16;
using f32x4  = __attribute__((ext_vector_type(4))) float;

__device__ __forceinline__ float sspf(float v) {
    const float t = __expf(-fabsf(v));
    return fmaxf(v, 0.f) + __logf(1.f + t) - 0.69314718055994531f;
}
__device__ __forceinline__ unsigned short f2bf(float f) {
    union { float f; unsigned u; } v; v.f = f;
    unsigned r = v.u + 0x7fffu + ((v.u >> 16) & 1u);
    return (unsigned short)(r >> 16);
}
__device__ __forceinline__ float bf2f(unsigned short s) {
    union { unsigned u; float f; } v; v.u = ((unsigned)s) << 16;
    return v.f;
}

// Barrier WITHOUT vmcnt drain: LDS ordering only (T3/T4 pattern).
// lgkmcnt(0) commits this wave's LDS ops; s_barrier syncs waves; sched_barrier
// fences compiler motion (rule #18). vmcnt (gathers/atomics) stays in flight.
__device__ __forceinline__ void bar_nodrain() {
    __builtin_amdgcn_sched_barrier(0);
    asm volatile("s_waitcnt lgkmcnt(0)" ::: "memory");
    __builtin_amdgcn_s_barrier();
    __builtin_amdgcn_sched_barrier(0);
}

// ---------------------------------------------------------------------------
// Counting sort by idx_i only.
// ---------------------------------------------------------------------------
__global__ void hist1_kernel(const int* __restrict__ idx, int* __restrict__ deg, int E)
{
    for (int e = blockIdx.x * blockDim.x + threadIdx.x; e < E;
         e += gridDim.x * blockDim.x)
        atomicAdd(&deg[idx[e]], 1);
}

__global__ void scanA1_kernel(const int* __restrict__ deg, int* __restrict__ loc,
                              int* __restrict__ parts, int NN)
{
    const int tid = threadIdx.x;
    const int base = blockIdx.x * 2048;
    __shared__ int tsum[256];
    int v[8]; int s = 0;
    #pragma unroll
    for (int r = 0; r < 8; ++r) {
        const int idx = base + tid * 8 + r;
        v[r] = (idx < NN) ? deg[idx] : 0;
        s += v[r];
    }
    tsum[tid] = s;
    __syncthreads();
    #pragma unroll
    for (int d = 1; d < 256; d <<= 1) {
        const int add = (tid >= d) ? tsum[tid - d] : 0;
        __syncthreads();
        tsum[tid] += add;
        __syncthreads();
    }
    int run = tsum[tid] - s;
    #pragma unroll
    for (int r = 0; r < 8; ++r) {
        const int idx = base + tid * 8 + r;
        if (idx < NN) loc[idx] = run;
        run += v[r];
    }
    if (tid == 0) parts[blockIdx.x] = tsum[255];
}

__global__ void scanB1_kernel(int* __restrict__ parts, int NB)
{
    __shared__ int p[64];
    const int t = threadIdx.x;
    p[t] = (t < NB) ? parts[t] : 0;
    __syncthreads();
    #pragma unroll
    for (int d = 1; d < 64; d <<= 1) {
        const int add = (t >= d) ? p[t - d] : 0;
        __syncthreads();
        p[t] += add;
        __syncthreads();
    }
    parts[t] = (t > 0) ? p[t - 1] : 0;
}

__global__ void scanC1_kernel(const int* __restrict__ loc, const int* __restrict__ parts,
                              int* __restrict__ rowp, int* __restrict__ cur, int NN)
{
    for (int i = blockIdx.x * blockDim.x + threadIdx.x; i < NN;
         i += gridDim.x * blockDim.x) {
        const int v = loc[i] + parts[i >> 11];
        rowp[i] = v;
        cur[i]  = v;
    }
}

__global__ void scatter1_kernel(const int* __restrict__ idx, int* __restrict__ cur,
                                int* __restrict__ ord, int E)
{
    for (int e = blockIdx.x * blockDim.x + threadIdx.x; e < E;
         e += gridDim.x * blockDim.x) {
        const int p = atomicAdd(&cur[idx[e]], 1);
        ord[p] = e;
    }
}

// ---------------------------------------------------------------------------
// Hybrid edge kernel, persistent (512 thr = 8 waves, 16 cols/wave, (512,2)).
// r16 structure; ALL tile-loop barriers are no-vmcnt-drain (bar_nodrain).
// ---------------------------------------------------------------------------
__global__ __launch_bounds__(512, 2)
void edge_hybrid_kernel(const float* __restrict__ f_ij,
                        const float* __restrict__ rcut,
                        const int* __restrict__ idx_i,
                        const int* __restrict__ idx_j,
                        const float* __restrict__ Wf1,
                        const float* __restrict__ bf1,
                        const float* __restrict__ Wf2,
                        const float* __restrict__ bf2v,
                        const _Float16* __restrict__ xf,
                        const _Float16* __restrict__ yf,
                        const int* __restrict__ ord,
                        const int* __restrict__ rowp,
                        float* __restrict__ conv_x,
                        float* __restrict__ conv_y,
                        int NN, int E, int nGroups)
{
    const int tid = threadIdx.x;
    const int l = tid & 63, w = tid >> 6;
    const int lr = l & 15, lk = l >> 4;
    const int wcol = w * 16 + lr;

    __shared__ _Float16 M_s[64 * 137];     // f-staging alias (stride 40), then M
    __shared__ _Float16 Ash[64 * 136];     // h (XOR swizzle), then g
    __shared__ _Float16 xown[32 * 136];
    __shared__ int ni_s[64];
    __shared__ int jo_s[64];
    __shared__ float rc_s[64];

    _Float16* fst = M_s;

    half8 b1fr;
    #pragma unroll
    for (int j = 0; j < 8; ++j) {
        const int k = lk * 8 + j;
        b1fr[j] = (k < RBF) ? (_Float16)Wf1[k * NF + wcol] : (_Float16)0.f;
    }
    half8 b2fr[4];
    #pragma unroll
    for (int kb = 0; kb < 4; ++kb)
        #pragma unroll
        for (int j = 0; j < 8; ++j)
            b2fr[kb][j] = (_Float16)Wf2[(size_t)(kb * 32 + lk * 8 + j) * NF + wcol];
    const float b1c = bf1[wcol];
    const float b2c = bf2v[wcol];

    for (int grp = blockIdx.x; grp < nGroups; grp += gridDim.x) {
        const int n0 = grp * 32;
        const int eb = rowp[n0];
        const int ee = (n0 + 32 < NN) ? rowp[n0 + 32] : E;
        const int nt = (ee - eb + 63) >> 6;

        // stage own xf rows [n0, n0+32): 2048 uints, stride 136
        #pragma unroll
        for (int u = 0; u < 4; ++u) {
            const int tt = u * 512 + tid;
            const int row = tt >> 6, cp = tt & 63;
            unsigned v = 0;
            if (n0 + row < NN)
                v = reinterpret_cast<const unsigned*>(xf)[(size_t)(n0 + row) * 64 + cp];
            *reinterpret_cast<unsigned*>(&xown[row * 136 + cp * 2]) = v;
        }

        f32x4 accS[2] = {};

        for (int t = 0; t < nt; ++t) {
            const int p0 = eb + t * 64;
            const int cnt = ee - p0;
            bar_nodrain();                 // prev-tile LDS readers done

            if (tid < 64) {
                const int p = p0 + tid;
                const bool val = p < ee;
                const int e = val ? ord[p] : 0;
                ni_s[tid] = val ? idx_i[e] : -1;
                jo_s[tid] = val ? idx_j[e] * NF : 0;
                rc_s[tid] = val ? rcut[e] : 0.f;
            }
            #pragma unroll
            for (int s4 = 0; s4 < 4; ++s4) {
                const int tt = s4 * 512 + tid;
                const int row = tt >> 5, k = tt & 31;
                const int p = p0 + row;
                float v = 0.f;
                if (k < RBF && p < ee) v = f_ij[(size_t)ord[p] * RBF + k];
                fst[row * 40 + k] = (_Float16)v;
            }
            bar_nodrain();

            // phase 1: h = ssp(f @ W1 + b1) -> Ash (XOR swizzle, stride 136)
            f32x4 acc1[4] = {};
            #pragma unroll
            for (int rb = 0; rb < 4; ++rb) {
                const half8 a = *reinterpret_cast<const half8*>(
                    &fst[(rb * 16 + lr) * 40 + lk * 8]);
                acc1[rb] = __builtin_amdgcn_mfma_f32_16x16x32_f16(a, b1fr, acc1[rb], 0, 0, 0);
            }
            #pragma unroll
            for (int rb = 0; rb < 4; ++rb)
                #pragma unroll
                for (int q = 0; q < 4; ++q) {
                    const int e = rb * 16 + lk * 4 + q;
                    const float hv = sspf(acc1[rb][q] + b1c);
                    Ash[e * 136 + (wcol ^ ((e & 7) << 3))] = (_Float16)hv;
                }
            bar_nodrain();

            // EARLY: issue g gather loads (latency hides under phase-2 MFMA)
            unsigned gr[8];
            #pragma unroll
            for (int u = 0; u < 8; ++u) {
                const int tt = u * 512 + tid;
                const int slot = tt >> 6, cp = tt & 63;
                gr[u] = reinterpret_cast<const unsigned*>(yf)[(jo_s[slot] >> 1) + cp];
            }

            // phase 2: wij = h @ W2
            f32x4 acc2[4] = {};
            #pragma unroll
            for (int rb = 0; rb < 4; ++rb) {
                half8 a[4];
                #pragma unroll
                for (int kb = 0; kb < 4; ++kb) {
                    const int e  = rb * 16 + lr;
                    const int k0 = kb * 32 + lk * 8;
                    a[kb] = *reinterpret_cast<const half8*>(
                        &Ash[e * 136 + (k0 ^ ((e & 7) << 3))]);
                }
                #pragma unroll
                for (int kb = 0; kb < 4; ++kb)
                    acc2[rb] = __builtin_amdgcn_mfma_f32_16x16x32_f16(
                        a[kb], b2fr[kb], acc2[rb], 0, 0, 0);
            }
            bar_nodrain();              // h reads done -> Ash reusable for g

            // g ds_writes into Ash (stride 136) from prefetched registers
            #pragma unroll
            for (int u = 0; u < 8; ++u) {
                const int tt = u * 512 + tid;
                const int slot = tt >> 6, cp = tt & 63;
                *reinterpret_cast<unsigned*>(&Ash[slot * 136 + cp * 2]) = gr[u];
            }
            bar_nodrain();

            // per-thread: M = wv*g -> M_s (f dead) + y-side atomics (valid slots)
            #pragma unroll
            for (int rb = 0; rb < 4; ++rb)
                #pragma unroll
                for (int q = 0; q < 4; ++q) {
                    const int e = rb * 16 + lk * 4 + q;
                    const float wv = (acc2[rb][q] + b2c) * rc_s[e];
                    const float g  = (float)Ash[e * 136 + wcol];
                    M_s[e * 137 + wcol] = (_Float16)(wv * g);
                    if (e < cnt) {
                        const int oi = ni_s[e] - n0;
                        const float xo = (float)xown[oi * 136 + wcol];
                        unsafeAtomicAdd(&conv_y[(size_t)jo_s[e] + wcol], xo * wv);
                    }
                }
            bar_nodrain();

            // phase 3: accS += S @ M  (selector one-hot)
            #pragma unroll
            for (int kb2 = 0; kb2 < 2; ++kb2) {
                half8 bm;
                int nn[8];
                #pragma unroll
                for (int j = 0; j < 8; ++j) {
                    bm[j] = M_s[(kb2 * 32 + lk * 8 + j) * 137 + wcol];
                    nn[j] = ni_s[kb2 * 32 + lk * 8 + j];
                }
                #pragma unroll
                for (int rb2 = 0; rb2 < 2; ++rb2) {
                    const int node = n0 + rb2 * 16 + lr;
                    half8 as;
                    #pragma unroll
                    for (int j = 0; j < 8; ++j)
                        as[j] = (nn[j] == node) ? (_Float16)1.f : (_Float16)0.f;
                    accS[rb2] = __builtin_amdgcn_mfma_f32_16x16x32_f16(
                        as, bm, accS[rb2], 0, 0, 0);
                }
            }
        }

        // conv_x rows [n0, n0+32): written once, plain stores
        #pragma unroll
        for (int rb2 = 0; rb2 < 2; ++rb2)
            #pragma unroll
            for (int q = 0; q < 4; ++q) {
                const int n = n0 + rb2 * 16 + lk * 4 + q;
                if (n < NN) conv_x[(size_t)n * NF + wcol] = accS[rb2][q];
            }
        bar_nodrain();                     // xown safe to restage next group
    }
}

// ---------------------------------------------------------------------------
// Projection (persistent, f16): out_f16 = in @ W (bias-free) + zero conv_y
// ---------------------------------------------------------------------------
__global__ __launch_bounds__(256, 2)
void proj_mfma_kernel(const float* in0, const float* in1,
                      const float* __restrict__ W0, const float* __restrict__ W1p,
                      _Float16* o0, _Float16* o1,
                      float* __restrict__ conv_y, int N, int nTiles)
{
    const float* in = blockIdx.y ? in1 : in0;
    const float* W  = blockIdx.y ? W1p : W0;
    _Float16* out   = blockIdx.y ? o1 : o0;

    const int tid = threadIdx.x;
    const int l = tid & 63, w = tid >> 6;
    const int lr = l & 15, lk = l >> 4;
    const int wcol0 = w * 32;

    __shared__ _Float16 Ahi[64 * NF];

    half8 bfr[4][2];
    #pragma unroll
    for (int kb = 0; kb < 4; ++kb)
        #pragma unroll
        for (int cb = 0; cb < 2; ++cb) {
            const int col = wcol0 + cb * 16 + lr;
            #pragma unroll
            for (int j = 0; j < 8; ++j)
                bfr[kb][cb][j] = (_Float16)W[(size_t)(kb * 32 + lk * 8 + j) * NF + col];
        }

    for (int tile = blockIdx.x; tile < nTiles; tile += gridDim.x) {
        const int n0 = tile * 64;
        __syncthreads();
        #pragma unroll
        for (int s = 0; s < 32; ++s) {
            const int t = s * 256 + tid;
            const int row = t >> 7, cc = t & (NF - 1);
            const float v = (n0 + row < N) ? in[(size_t)(n0 + row) * NF + cc] : 0.f;
            Ahi[row * NF + (cc ^ ((row & 7) << 3))] = (_Float16)v;
        }
        {
            const float4 z = {0.f, 0.f, 0.f, 0.f};
            const int rbase = n0 + 32 * blockIdx.y;
            #pragma unroll
            for (int s = 0; s < 4; ++s) {
                const int t = s * 256 + tid;
                const int row = rbase + (t >> 5);
                if (row < N)
                    *reinterpret_cast<float4*>(&conv_y[(size_t)row * NF + (t & 31) * 4]) = z;
            }
        }
        __syncthreads();

        f32x4 acc[4][2] = {};
        #pragma unroll
        for (int rb = 0; rb < 4; ++rb) {
            half8 a[4];
            #pragma unroll
            for (int kb = 0; kb < 4; ++kb) {
                const int e  = rb * 16 + lr;
                const int k0 = kb * 32 + lk * 8;
                a[kb] = *reinterpret_cast<const half8*>(&Ahi[e * NF + (k0 ^ ((e & 7) << 3))]);
            }
            #pragma unroll
            for (int cb = 0; cb < 2; ++cb)
                #pragma unroll
                for (int kb = 0; kb < 4; ++kb)
                    acc[rb][cb] = __builtin_amdgcn_mfma_f32_16x16x32_f16(
                        a[kb], bfr[kb][cb], acc[rb][cb], 0, 0, 0);
        }

        #pragma unroll
        for (int rb = 0; rb < 4; ++rb)
            #pragma unroll
            for (int cb = 0; cb < 2; ++cb) {
                const int col = wcol0 + cb * 16 + lr;
                #pragma unroll
                for (int q = 0; q < 4; ++q) {
                    const int n = n0 + rb * 16 + lk * 4 + q;
                    if (n < N) out[(size_t)n * NF + col] = (_Float16)acc[rb][cb][q];
                }
            }
    }
}

// ---------------------------------------------------------------------------
// Fused output MLP (persistent): out = ssp(conv @ W1 + b1) @ W2 + b2
// split-bf16 (hi/lo) A for near-fp32 precision.
// ---------------------------------------------------------------------------
__global__ __launch_bounds__(256, 2)
void out_fused_kernel(const float* conv0, const float* conv1,
                      const float* __restrict__ W10, const float* __restrict__ W11,
                      const float* __restrict__ b10, const float* __restrict__ b11,
                      const float* __restrict__ W20, const float* __restrict__ W21,
                      const float* __restrict__ b20, const float* __restrict__ b21,
                      float* o0, float* o1, int N, int nTiles)
{
    const float* in = blockIdx.y ? conv1 : conv0;
    const float* W1 = blockIdx.y ? W11 : W10;
    const float* b1 = blockIdx.y ? b11 : b10;
    const float* W2 = blockIdx.y ? W21 : W20;
    const float* b2 = blockIdx.y ? b21 : b20;
    float* out      = blockIdx.y ? o1  : o0;

    const int tid = threadIdx.x;
    const int l = tid & 63, w = tid >> 6;
    const int lr = l & 15, lk = l >> 4;
    const int wcol0 = w * 32;

    __shared__ unsigned short Ahi[64 * NF];
    __shared__ unsigned short Alo[64 * NF];

    short8 w1fr[4][2], w2fr[4][2];
    #pragma unroll
    for (int kb = 0; kb < 4; ++kb)
        #pragma unroll
        for (int cb = 0; cb < 2; ++cb) {
            const int col = wcol0 + cb * 16 + lr;
            #pragma unroll
            for (int j = 0; j < 8; ++j) {
                const size_t kk = (size_t)(kb * 32 + lk * 8 + j) * NF + col;
                w1fr[kb][cb][j] = (short)f2bf(W1[kk]);
                w2fr[kb][cb][j] = (short)f2bf(W2[kk]);
            }
        }
    const float b1c0 = b1[wcol0 + lr], b1c1 = b1[wcol0 + 16 + lr];
    const float b2c0 = b2[wcol0 + lr], b2c1 = b2[wcol0 + 16 + lr];

    for (int tile = blockIdx.x; tile < nTiles; tile += gridDim.x) {
        const int n0 = tile * 64;
        __syncthreads();
        #pragma unroll
        for (int s = 0; s < 32; ++s) {
            const int t = s * 256 + tid;
            const int row = t >> 7, cc = t & (NF - 1);
            const float v = (n0 + row < N) ? in[(size_t)(n0 + row) * NF + cc] : 0.f;
            const unsigned short hi = f2bf(v);
            const int idx = row * NF + (cc ^ ((row & 7) << 3));
            Ahi[idx] = hi;
            Alo[idx] = f2bf(v - bf2f(hi));
        }
        __syncthreads();

        f32x4 acc1[4][2] = {};
        #pragma unroll
        for (int rb = 0; rb < 4; ++rb) {
            short8 ah[4], al[4];
            #pragma unroll
            for (int kb = 0; kb < 4; ++kb) {
                const int e  = rb * 16 + lr;
                const int k0 = kb * 32 + lk * 8;
                const int idx = e * NF + (k0 ^ ((e & 7) << 3));
                ah[kb] = *reinterpret_cast<const short8*>(&Ahi[idx]);
                al[kb] = *reinterpret_cast<const short8*>(&Alo[idx]);
            }
            #pragma unroll
            for (int cb = 0; cb < 2; ++cb)
                #pragma unroll
                for (int kb = 0; kb < 4; ++kb) {
                    acc1[rb][cb] = __builtin_amdgcn_mfma_f32_16x16x32_bf16(
                        ah[kb], w1fr[kb][cb], acc1[rb][cb], 0, 0, 0);
                    acc1[rb][cb] = __builtin_amdgcn_mfma_f32_16x16x32_bf16(
                        al[kb], w1fr[kb][cb], acc1[rb][cb], 0, 0, 0);
                }
        }
        __syncthreads();

        #pragma unroll
        for (int rb = 0; rb < 4; ++rb)
            #pragma unroll
            for (int cb = 0; cb < 2; ++cb) {
                const int col = wcol0 + cb * 16 + lr;
                #pragma unroll
                for (int q = 0; q < 4; ++q) {
                    const int e = rb * 16 + lk * 4 + q;
                    const float hv = sspf(acc1[rb][cb][q] + (cb ? b1c1 : b1c0));
                    const unsigned short hi = f2bf(hv);
                    const int idx = e * NF + (col ^ ((e & 7) << 3));
                    Ahi[idx] = hi;
                    Alo[idx] = f2bf(hv - bf2f(hi));
                }
            }
        __syncthreads();

        f32x4 acc2[4][2] = {};
        #pragma unroll
        for (int rb = 0; rb < 4; ++rb) {
            short8 ah[4], al[4];
            #pragma unroll
            for (int kb = 0; kb < 4; ++kb) {
                const int e  = rb * 16 + lr;
                const int k0 = kb * 32 + lk * 8;
                const int idx = e * NF + (k0 ^ ((e & 7) << 3));
                ah[kb] = *reinterpret_cast<const short8*>(&Ahi[idx]);
                al[kb] = *reinterpret_cast<const short8*>(&Alo[idx]);
            }
            #pragma unroll
            for (int cb = 0; cb < 2; ++cb)
                #pragma unroll
                for (int kb = 0; kb < 4; ++kb) {
                    acc2[rb][cb] = __builtin_amdgcn_mfma_f32_16x16x32_bf16(
                        ah[kb], w2fr[kb][cb], acc2[rb][cb], 0, 0, 0);
                    acc2[rb][cb] = __builtin_amdgcn_mfma_f32_16x16x32_bf16(
                        al[kb], w2fr[kb][cb], acc2[rb][cb], 0, 0, 0);
                }
        }

        #pragma unroll
        for (int rb = 0; rb < 4; ++rb)
            #pragma unroll
            for (int cb = 0; cb < 2; ++cb) {
                const int col = wcol0 + cb * 16 + lr;
                #pragma unroll
                for (int q = 0; q < 4; ++q) {
                    const int n = n0 + rb * 16 + lk * 4 + q;
                    if (n < N)
                        out[(size_t)n * NF + col] = acc2[rb][cb][q] + (cb ? b2c1 : b2c0);
                }
            }
    }
}

extern "C" void kernel_launch(void* const* d_in, const int* in_sizes, int n_in,
                              void* d_out, int out_size, void* d_ws, size_t ws_size,
                              hipStream_t stream)
{
    const float* x    = (const float*)d_in[0];
    const float* y    = (const float*)d_in[1];
    const float* f_ij = (const float*)d_in[2];
    const float* rcut = (const float*)d_in[3];
    const int* idx_i  = (const int*)d_in[4];
    const int* idx_j  = (const int*)d_in[5];
    const float* W_in2f   = (const float*)d_in[6];
    const float* W_in2f_y = (const float*)d_in[7];
    const float* Wf1 = (const float*)d_in[8];
    const float* bf1 = (const float*)d_in[9];
    const float* Wf2 = (const float*)d_in[10];
    const float* bf2 = (const float*)d_in[11];
    const float* Wx1 = (const float*)d_in[12];
    const float* bx1 = (const float*)d_in[13];
    const float* Wx2 = (const float*)d_in[14];
    const float* bx2 = (const float*)d_in[15];
    const float* Wy1 = (const float*)d_in[16];
    const float* by1 = (const float*)d_in[17];
    const float* Wy2 = (const float*)d_in[18];
    const float* by2 = (const float*)d_in[19];

    const int N = in_sizes[0] / NF;
    const int E = in_sizes[4];
    const size_t NNF = (size_t)N * NF;

    _Float16* xf = (_Float16*)d_out;
    _Float16* yf = xf + NNF;
    float* ox = (float*)d_out;
    float* oy = ox + NNF;

    int* sb    = (int*)((char*)d_out + 4 * NNF);
    int* deg   = sb;
    int* loc   = sb + N;
    int* rowp  = sb + 2 * N;
    int* cur   = sb + 3 * N;
    int* parts = sb + 4 * N;
    int* ord   = sb + 4 * N + 64;

    float* conv_x = (float*)d_ws;
    float* conv_y = conv_x + NNF;

    const int NB = (N + 2047) / 2048;
    const int nodeTiles = (N + 63) / 64;
    const int nGroups = (N + 31) / 32;

    hipMemsetAsync(deg, 0, (size_t)N * sizeof(int), stream);

    proj_mfma_kernel<<<dim3(1024, 2), 256, 0, stream>>>(
        x, y, W_in2f, W_in2f_y, xf, yf, conv_y, N, nodeTiles);

    hist1_kernel<<<1024, 256, 0, stream>>>(idx_i, deg, E);
    scanA1_kernel<<<NB, 256, 0, stream>>>(deg, loc, parts, N);
    scanB1_kernel<<<1, 64, 0, stream>>>(parts, NB);
    scanC1_kernel<<<128, 256, 0, stream>>>(loc, parts, rowp, cur, N);
    scatter1_kernel<<<1024, 256, 0, stream>>>(idx_i, cur, ord, E);

    edge_hybrid_kernel<<<1024, 512, 0, stream>>>(
        f_ij, rcut, idx_i, idx_j, Wf1, bf1, Wf2, bf2, xf, yf,
        ord, rowp, conv_x, conv_y, N, E, nGroups);

    out_fused_kernel<<<dim3(1024, 2), 256, 0, stream>>>(
        conv_x, conv_y, Wx1, Wy1, bx1, by1, Wx2, Wy2, bx2, by2,
        ox, oy, N, nodeTiles);
}

// Round 18
// 737.814 us; speedup vs baseline: 1.0333x; 1.0333x over previous
//
#include <hip/hip_runtime.h>
#include <hip/hip_bf16.h>

#define NF 128
#define RBF 20

using short8 = __attribute__((ext_vector_type(8))) short;
using half8  = __attribute__((ext_vector_type(8))) _Float16;
using f32x4  = __attribute__((ext_vector_type(4))) float;

__device__ __forceinline__ float sspf(float v) {
    const float t = __expf(-fabsf(v));
    return fmaxf(v, 0.f) + __logf(1.f + t) - 0.69314718055994531f;
}
__device__ __forceinline__ unsigned short f2bf(float f) {
    union { float f; unsigned u; } v; v.f = f;
    unsigned r = v.u + 0x7fffu + ((v.u >> 16) & 1u);
    return (unsigned short)(r >> 16);
}
__device__ __forceinline__ float bf2f(unsigned short s) {
    union { unsigned u; float f; } v; v.u = ((unsigned)s) << 16;
    return v.f;
}

// ---------------------------------------------------------------------------
// Counting sort by idx_i only.
// ---------------------------------------------------------------------------
__global__ void hist1_kernel(const int* __restrict__ idx, int* __restrict__ deg, int E)
{
    for (int e = blockIdx.x * blockDim.x + threadIdx.x; e < E;
         e += gridDim.x * blockDim.x)
        atomicAdd(&deg[idx[e]], 1);
}

__global__ void scanA1_kernel(const int* __restrict__ deg, int* __restrict__ loc,
                              int* __restrict__ parts, int NN)
{
    const int tid = threadIdx.x;
    const int base = blockIdx.x * 2048;
    __shared__ int tsum[256];
    int v[8]; int s = 0;
    #pragma unroll
    for (int r = 0; r < 8; ++r) {
        const int idx = base + tid * 8 + r;
        v[r] = (idx < NN) ? deg[idx] : 0;
        s += v[r];
    }
    tsum[tid] = s;
    __syncthreads();
    #pragma unroll
    for (int d = 1; d < 256; d <<= 1) {
        const int add = (tid >= d) ? tsum[tid - d] : 0;
        __syncthreads();
        tsum[tid] += add;
        __syncthreads();
    }
    int run = tsum[tid] - s;
    #pragma unroll
    for (int r = 0; r < 8; ++r) {
        const int idx = base + tid * 8 + r;
        if (idx < NN) loc[idx] = run;
        run += v[r];
    }
    if (tid == 0) parts[blockIdx.x] = tsum[255];
}

__global__ void scanB1_kernel(int* __restrict__ parts, int NB)
{
    __shared__ int p[64];
    const int t = threadIdx.x;
    p[t] = (t < NB) ? parts[t] : 0;
    __syncthreads();
    #pragma unroll
    for (int d = 1; d < 64; d <<= 1) {
        const int add = (t >= d) ? p[t - d] : 0;
        __syncthreads();
        p[t] += add;
        __syncthreads();
    }
    parts[t] = (t > 0) ? p[t - 1] : 0;
}

__global__ void scanC1_kernel(const int* __restrict__ loc, const int* __restrict__ parts,
                              int* __restrict__ rowp, int* __restrict__ cur, int NN)
{
    for (int i = blockIdx.x * blockDim.x + threadIdx.x; i < NN;
         i += gridDim.x * blockDim.x) {
        const int v = loc[i] + parts[i >> 11];
        rowp[i] = v;
        cur[i]  = v;
    }
}

__global__ void scatter1_kernel(const int* __restrict__ idx, int* __restrict__ cur,
                                int* __restrict__ ord, int E)
{
    for (int e = blockIdx.x * blockDim.x + threadIdx.x; e < E;
         e += gridDim.x * blockDim.x) {
        const int p = atomicAdd(&cur[idx[e]], 1);
        ord[p] = e;
    }
}

// ---------------------------------------------------------------------------
// Hybrid edge kernel v2: 256 threads (4 waves), 16-node groups, 32-edge tiles.
// ~22 KB LDS + natural VGPR (~110) -> 4 blocks/CU = 4 independent barrier
// domains (2x r16) for latency hiding. Same algorithm: selector-MFMA conv_x
// (plain stores) + halved fp32 atomics conv_y.
// Wave owns 32 cols (2 col-blocks of 16).
// ---------------------------------------------------------------------------
__global__ __launch_bounds__(256, 2)
void edge_hybrid_kernel(const float* __restrict__ f_ij,
                        const float* __restrict__ rcut,
                        const int* __restrict__ idx_i,
                        const int* __restrict__ idx_j,
                        const float* __restrict__ Wf1,
                        const float* __restrict__ bf1,
                        const float* __restrict__ Wf2,
                        const float* __restrict__ bf2v,
                        const _Float16* __restrict__ xf,
                        const _Float16* __restrict__ yf,
                        const int* __restrict__ ord,
                        const int* __restrict__ rowp,
                        float* __restrict__ conv_x,
                        float* __restrict__ conv_y,
                        int NN, int E, int nGroups)
{
    const int tid = threadIdx.x;
    const int l = tid & 63, w = tid >> 6;      // 4 waves
    const int lr = l & 15, lk = l >> 4;
    const int wcol0 = w * 32;                  // wave's 32-col slice

    __shared__ _Float16 M_s[32 * 137];         // 8.7 KB; first 32*40 aliases f-staging
    __shared__ _Float16 Ash[32 * 136];         // 8.5 KB: h (XOR swz) then g
    __shared__ _Float16 xown[16 * 136];        // 4.3 KB
    __shared__ int ni_s[32];
    __shared__ int jo_s[32];
    __shared__ float rc_s[32];

    _Float16* fst = M_s;                       // f staging, stride 40

    // persistent weight fragments (32 cols per wave)
    half8 b1fr[2];
    #pragma unroll
    for (int cb = 0; cb < 2; ++cb) {
        const int col = wcol0 + cb * 16 + lr;
        #pragma unroll
        for (int j = 0; j < 8; ++j) {
            const int k = lk * 8 + j;
            b1fr[cb][j] = (k < RBF) ? (_Float16)Wf1[k * NF + col] : (_Float16)0.f;
        }
    }
    half8 b2fr[4][2];
    #pragma unroll
    for (int kb = 0; kb < 4; ++kb)
        #pragma unroll
        for (int cb = 0; cb < 2; ++cb) {
            const int col = wcol0 + cb * 16 + lr;
            #pragma unroll
            for (int j = 0; j < 8; ++j)
                b2fr[kb][cb][j] = (_Float16)Wf2[(size_t)(kb * 32 + lk * 8 + j) * NF + col];
        }
    const float b1c[2] = { bf1[wcol0 + lr], bf1[wcol0 + 16 + lr] };
    const float b2c[2] = { bf2v[wcol0 + lr], bf2v[wcol0 + 16 + lr] };

    for (int grp = blockIdx.x; grp < nGroups; grp += gridDim.x) {
        const int n0 = grp * 16;
        const int eb = rowp[n0];
        const int ee = (n0 + 16 < NN) ? rowp[n0 + 16] : E;
        const int nt = (ee - eb + 31) >> 5;

        // stage own xf rows [n0, n0+16): 1024 uints, stride 136
        #pragma unroll
        for (int u = 0; u < 4; ++u) {
            const int tt = u * 256 + tid;
            const int row = tt >> 6, cp = tt & 63;
            unsigned v = 0;
            if (n0 + row < NN)
                v = reinterpret_cast<const unsigned*>(xf)[(size_t)(n0 + row) * 64 + cp];
            *reinterpret_cast<unsigned*>(&xown[row * 136 + cp * 2]) = v;
        }

        f32x4 accS[2] = {};   // 16 nodes x (2 col-blocks of 16)

        for (int t = 0; t < nt; ++t) {
            const int p0 = eb + t * 32;
            const int cnt = ee - p0;
            __syncthreads();               // prev-tile LDS readers done (covers xown)

            if (tid < 32) {
                const int p = p0 + tid;
                const bool val = p < ee;
                const int e = val ? ord[p] : 0;
                ni_s[tid] = val ? idx_i[e] : -1;
                jo_s[tid] = val ? idx_j[e] * NF : 0;
                rc_s[tid] = val ? rcut[e] : 0.f;
            }
            // stage f tile: 32 rows x 32 k (padded) = 1024 elems / 256 thr
            #pragma unroll
            for (int s4 = 0; s4 < 4; ++s4) {
                const int tt = s4 * 256 + tid;
                const int row = tt >> 5, k = tt & 31;
                const int p = p0 + row;
                float v = 0.f;
                if (k < RBF && p < ee) v = f_ij[(size_t)ord[p] * RBF + k];
                fst[row * 40 + k] = (_Float16)v;
            }
            __syncthreads();

            // phase 1: h = ssp(f @ W1 + b1) -> Ash (XOR swz, stride 136)
            f32x4 acc1[2][2] = {};
            #pragma unroll
            for (int rb = 0; rb < 2; ++rb) {
                const half8 a = *reinterpret_cast<const half8*>(
                    &fst[(rb * 16 + lr) * 40 + lk * 8]);
                #pragma unroll
                for (int cb = 0; cb < 2; ++cb)
                    acc1[rb][cb] = __builtin_amdgcn_mfma_f32_16x16x32_f16(
                        a, b1fr[cb], acc1[rb][cb], 0, 0, 0);
            }
            #pragma unroll
            for (int rb = 0; rb < 2; ++rb)
                #pragma unroll
                for (int cb = 0; cb < 2; ++cb) {
                    const int col = wcol0 + cb * 16 + lr;
                    #pragma unroll
                    for (int q = 0; q < 4; ++q) {
                        const int e = rb * 16 + lk * 4 + q;
                        const float hv = sspf(acc1[rb][cb][q] + b1c[cb]);
                        Ash[e * 136 + (col ^ ((e & 7) << 3))] = (_Float16)hv;
                    }
                }
            __syncthreads();

            // EARLY: issue g gather loads (hide under phase-2 MFMA)
            unsigned gr[8];
            #pragma unroll
            for (int u = 0; u < 8; ++u) {
                const int tt = u * 256 + tid;
                const int slot = tt >> 6, cp = tt & 63;
                gr[u] = reinterpret_cast<const unsigned*>(yf)[(jo_s[slot] >> 1) + cp];
            }

            // phase 2: wij = h @ W2
            f32x4 acc2[2][2] = {};
            #pragma unroll
            for (int rb = 0; rb < 2; ++rb) {
                half8 a[4];
                #pragma unroll
                for (int kb = 0; kb < 4; ++kb) {
                    const int e  = rb * 16 + lr;
                    const int k0 = kb * 32 + lk * 8;
                    a[kb] = *reinterpret_cast<const half8*>(
                        &Ash[e * 136 + (k0 ^ ((e & 7) << 3))]);
                }
                #pragma unroll
                for (int cb = 0; cb < 2; ++cb)
                    #pragma unroll
                    for (int kb = 0; kb < 4; ++kb)
                        acc2[rb][cb] = __builtin_amdgcn_mfma_f32_16x16x32_f16(
                            a[kb], b2fr[kb][cb], acc2[rb][cb], 0, 0, 0);
            }
            __syncthreads();            // h reads done -> Ash reusable for g

            // g ds_writes into Ash (stride 136) from prefetched registers
            #pragma unroll
            for (int u = 0; u < 8; ++u) {
                const int tt = u * 256 + tid;
                const int slot = tt >> 6, cp = tt & 63;
                *reinterpret_cast<unsigned*>(&Ash[slot * 136 + cp * 2]) = gr[u];
            }
            __syncthreads();

            // per-thread: M = wv*g -> M_s (f dead) + y-side atomics (valid slots)
            #pragma unroll
            for (int rb = 0; rb < 2; ++rb)
                #pragma unroll
                for (int cb = 0; cb < 2; ++cb) {
                    const int col = wcol0 + cb * 16 + lr;
                    #pragma unroll
                    for (int q = 0; q < 4; ++q) {
                        const int e = rb * 16 + lk * 4 + q;
                        const float wv = (acc2[rb][cb][q] + b2c[cb]) * rc_s[e];
                        const float g  = (float)Ash[e * 136 + col];
                        M_s[e * 137 + col] = (_Float16)(wv * g);
                        if (e < cnt) {
                            const int oi = ni_s[e] - n0;
                            const float xo = (float)xown[oi * 136 + col];
                            unsafeAtomicAdd(&conv_y[(size_t)jo_s[e] + col], xo * wv);
                        }
                    }
                }
            __syncthreads();

            // phase 3: accS += S @ M  (selector one-hot, K=32 in one step)
            {
                half8 as;
                int nn[8];
                #pragma unroll
                for (int j = 0; j < 8; ++j) nn[j] = ni_s[lk * 8 + j];
                const int node = n0 + lr;
                #pragma unroll
                for (int j = 0; j < 8; ++j)
                    as[j] = (nn[j] == node) ? (_Float16)1.f : (_Float16)0.f;
                #pragma unroll
                for (int cb = 0; cb < 2; ++cb) {
                    const int col = wcol0 + cb * 16 + lr;
                    half8 bm;
                    #pragma unroll
                    for (int j = 0; j < 8; ++j)
                        bm[j] = M_s[(lk * 8 + j) * 137 + col];
                    accS[cb] = __builtin_amdgcn_mfma_f32_16x16x32_f16(
                        as, bm, accS[cb], 0, 0, 0);
                }
            }
        }

        // conv_x rows [n0, n0+16): written once, plain stores
        #pragma unroll
        for (int cb = 0; cb < 2; ++cb) {
            const int col = wcol0 + cb * 16 + lr;
            #pragma unroll
            for (int q = 0; q < 4; ++q) {
                const int n = n0 + lk * 4 + q;
                if (n < NN) conv_x[(size_t)n * NF + col] = accS[cb][q];
            }
        }
        __syncthreads();                   // xown safe to restage next group
    }
}

// ---------------------------------------------------------------------------
// Projection (persistent, f16): out_f16 = in @ W (bias-free) + zero conv_y
// ---------------------------------------------------------------------------
__global__ __launch_bounds__(256, 2)
void proj_mfma_kernel(const float* in0, const float* in1,
                      const float* __restrict__ W0, const float* __restrict__ W1p,
                      _Float16* o0, _Float16* o1,
                      float* __restrict__ conv_y, int N, int nTiles)
{
    const float* in = blockIdx.y ? in1 : in0;
    const float* W  = blockIdx.y ? W1p : W0;
    _Float16* out   = blockIdx.y ? o1 : o0;

    const int tid = threadIdx.x;
    const int l = tid & 63, w = tid >> 6;
    const int lr = l & 15, lk = l >> 4;
    const int wcol0 = w * 32;

    __shared__ _Float16 Ahi[64 * NF];

    half8 bfr[4][2];
    #pragma unroll
    for (int kb = 0; kb < 4; ++kb)
        #pragma unroll
        for (int cb = 0; cb < 2; ++cb) {
            const int col = wcol0 + cb * 16 + lr;
            #pragma unroll
            for (int j = 0; j < 8; ++j)
                bfr[kb][cb][j] = (_Float16)W[(size_t)(kb * 32 + lk * 8 + j) * NF + col];
        }

    for (int tile = blockIdx.x; tile < nTiles; tile += gridDim.x) {
        const int n0 = tile * 64;
        __syncthreads();
        #pragma unroll
        for (int s = 0; s < 32; ++s) {
            const int t = s * 256 + tid;
            const int row = t >> 7, cc = t & (NF - 1);
            const float v = (n0 + row < N) ? in[(size_t)(n0 + row) * NF + cc] : 0.f;
            Ahi[row * NF + (cc ^ ((row & 7) << 3))] = (_Float16)v;
        }
        {
            const float4 z = {0.f, 0.f, 0.f, 0.f};
            const int rbase = n0 + 32 * blockIdx.y;
            #pragma unroll
            for (int s = 0; s < 4; ++s) {
                const int t = s * 256 + tid;
                const int row = rbase + (t >> 5);
                if (row < N)
                    *reinterpret_cast<float4*>(&conv_y[(size_t)row * NF + (t & 31) * 4]) = z;
            }
        }
        __syncthreads();

        f32x4 acc[4][2] = {};
        #pragma unroll
        for (int rb = 0; rb < 4; ++rb) {
            half8 a[4];
            #pragma unroll
            for (int kb = 0; kb < 4; ++kb) {
                const int e  = rb * 16 + lr;
                const int k0 = kb * 32 + lk * 8;
                a[kb] = *reinterpret_cast<const half8*>(&Ahi[e * NF + (k0 ^ ((e & 7) << 3))]);
            }
            #pragma unroll
            for (int cb = 0; cb < 2; ++cb)
                #pragma unroll
                for (int kb = 0; kb < 4; ++kb)
                    acc[rb][cb] = __builtin_amdgcn_mfma_f32_16x16x32_f16(
                        a[kb], bfr[kb][cb], acc[rb][cb], 0, 0, 0);
        }

        #pragma unroll
        for (int rb = 0; rb < 4; ++rb)
            #pragma unroll
            for (int cb = 0; cb < 2; ++cb) {
                const int col = wcol0 + cb * 16 + lr;
                #pragma unroll
                for (int q = 0; q < 4; ++q) {
                    const int n = n0 + rb * 16 + lk * 4 + q;
                    if (n < N) out[(size_t)n * NF + col] = (_Float16)acc[rb][cb][q];
                }
            }
    }
}

// ---------------------------------------------------------------------------
// Fused output MLP (persistent): out = ssp(conv @ W1 + b1) @ W2 + b2
// split-bf16 (hi/lo) A for near-fp32 precision.
// ---------------------------------------------------------------------------
__global__ __launch_bounds__(256, 2)
void out_fused_kernel(const float* conv0, const float* conv1,
                      const float* __restrict__ W10, const float* __restrict__ W11,
                      const float* __restrict__ b10, const float* __restrict__ b11,
                      const float* __restrict__ W20, const float* __restrict__ W21,
                      const float* __restrict__ b20, const float* __restrict__ b21,
                      float* o0, float* o1, int N, int nTiles)
{
    const float* in = blockIdx.y ? conv1 : conv0;
    const float* W1 = blockIdx.y ? W11 : W10;
    const float* b1 = blockIdx.y ? b11 : b10;
    const float* W2 = blockIdx.y ? W21 : W20;
    const float* b2 = blockIdx.y ? b21 : b20;
    float* out      = blockIdx.y ? o1  : o0;

    const int tid = threadIdx.x;
    const int l = tid & 63, w = tid >> 6;
    const int lr = l & 15, lk = l >> 4;
    const int wcol0 = w * 32;

    __shared__ unsigned short Ahi[64 * NF];
    __shared__ unsigned short Alo[64 * NF];

    short8 w1fr[4][2], w2fr[4][2];
    #pragma unroll
    for (int kb = 0; kb < 4; ++kb)
        #pragma unroll
        for (int cb = 0; cb < 2; ++cb) {
            const int col = wcol0 + cb * 16 + lr;
            #pragma unroll
            for (int j = 0; j < 8; ++j) {
                const size_t kk = (size_t)(kb * 32 + lk * 8 + j) * NF + col;
                w1fr[kb][cb][j] = (short)f2bf(W1[kk]);
                w2fr[kb][cb][j] = (short)f2bf(W2[kk]);
            }
        }
    const float b1c0 = b1[wcol0 + lr], b1c1 = b1[wcol0 + 16 + lr];
    const float b2c0 = b2[wcol0 + lr], b2c1 = b2[wcol0 + 16 + lr];

    for (int tile = blockIdx.x; tile < nTiles; tile += gridDim.x) {
        const int n0 = tile * 64;
        __syncthreads();
        #pragma unroll
        for (int s = 0; s < 32; ++s) {
            const int t = s * 256 + tid;
            const int row = t >> 7, cc = t & (NF - 1);
            const float v = (n0 + row < N) ? in[(size_t)(n0 + row) * NF + cc] : 0.f;
            const unsigned short hi = f2bf(v);
            const int idx = row * NF + (cc ^ ((row & 7) << 3));
            Ahi[idx] = hi;
            Alo[idx] = f2bf(v - bf2f(hi));
        }
        __syncthreads();

        f32x4 acc1[4][2] = {};
        #pragma unroll
        for (int rb = 0; rb < 4; ++rb) {
            short8 ah[4], al[4];
            #pragma unroll
            for (int kb = 0; kb < 4; ++kb) {
                const int e  = rb * 16 + lr;
                const int k0 = kb * 32 + lk * 8;
                const int idx = e * NF + (k0 ^ ((e & 7) << 3));
                ah[kb] = *reinterpret_cast<const short8*>(&Ahi[idx]);
                al[kb] = *reinterpret_cast<const short8*>(&Alo[idx]);
            }
            #pragma unroll
            for (int cb = 0; cb < 2; ++cb)
                #pragma unroll
                for (int kb = 0; kb < 4; ++kb) {
                    acc1[rb][cb] = __builtin_amdgcn_mfma_f32_16x16x32_bf16(
                        ah[kb], w1fr[kb][cb], acc1[rb][cb], 0, 0, 0);
                    acc1[rb][cb] = __builtin_amdgcn_mfma_f32_16x16x32_bf16(
                        al[kb], w1fr[kb][cb], acc1[rb][cb], 0, 0, 0);
                }
        }
        __syncthreads();

        #pragma unroll
        for (int rb = 0; rb < 4; ++rb)
            #pragma unroll
            for (int cb = 0; cb < 2; ++cb) {
                const int col = wcol0 + cb * 16 + lr;
                #pragma unroll
                for (int q = 0; q < 4; ++q) {
                    const int e = rb * 16 + lk * 4 + q;
                    const float hv = sspf(acc1[rb][cb][q] + (cb ? b1c1 : b1c0));
                    const unsigned short hi = f2bf(hv);
                    const int idx = e * NF + (col ^ ((e & 7) << 3));
                    Ahi[idx] = hi;
                    Alo[idx] = f2bf(hv - bf2f(hi));
                }
            }
        __syncthreads();

        f32x4 acc2[4][2] = {};
        #pragma unroll
        for (int rb = 0; rb < 4; ++rb) {
            short8 ah[4], al[4];
            #pragma unroll
            for (int kb = 0; kb < 4; ++kb) {
                const int e  = rb * 16 + lr;
                const int k0 = kb * 32 + lk * 8;
                const int idx = e * NF + (k0 ^ ((e & 7) << 3));
                ah[kb] = *reinterpret_cast<const short8*>(&Ahi[idx]);
                al[kb] = *reinterpret_cast<const short8*>(&Alo[idx]);
            }
            #pragma unroll
            for (int cb = 0; cb < 2; ++cb)
                #pragma unroll
                for (int kb = 0; kb < 4; ++kb) {
                    acc2[rb][cb] = __builtin_amdgcn_mfma_f32_16x16x32_bf16(
                        ah[kb], w2fr[kb][cb], acc2[rb][cb], 0, 0, 0);
                    acc2[rb][cb] = __builtin_amdgcn_mfma_f32_16x16x32_bf16(
                        al[kb], w2fr[kb][cb], acc2[rb][cb], 0, 0, 0);
                }
        }

        #pragma unroll
        for (int rb = 0; rb < 4; ++rb)
            #pragma unroll
            for (int cb = 0; cb < 2; ++cb) {
                const int col = wcol0 + cb * 16 + lr;
                #pragma unroll
                for (int q = 0; q < 4; ++q) {
                    const int n = n0 + rb * 16 + lk * 4 + q;
                    if (n < N)
                        out[(size_t)n * NF + col] = acc2[rb][cb][q] + (cb ? b2c1 : b2c0);
                }
            }
    }
}

extern "C" void kernel_launch(void* const* d_in, const int* in_sizes, int n_in,
                              void* d_out, int out_size, void* d_ws, size_t ws_size,
                              hipStream_t stream)
{
    const float* x    = (const float*)d_in[0];
    const float* y    = (const float*)d_in[1];
    const float* f_ij = (const float*)d_in[2];
    const float* rcut = (const float*)d_in[3];
    const int* idx_i  = (const int*)d_in[4];
    const int* idx_j  = (const int*)d_in[5];
    const float* W_in2f   = (const float*)d_in[6];
    const float* W_in2f_y = (const float*)d_in[7];
    const float* Wf1 = (const float*)d_in[8];
    const float* bf1 = (const float*)d_in[9];
    const float* Wf2 = (const float*)d_in[10];
    const float* bf2 = (const float*)d_in[11];
    const float* Wx1 = (const float*)d_in[12];
    const float* bx1 = (const float*)d_in[13];
    const float* Wx2 = (const float*)d_in[14];
    const float* bx2 = (const float*)d_in[15];
    const float* Wy1 = (const float*)d_in[16];
    const float* by1 = (const float*)d_in[17];
    const float* Wy2 = (const float*)d_in[18];
    const float* by2 = (const float*)d_in[19];

    const int N = in_sizes[0] / NF;
    const int E = in_sizes[4];
    const size_t NNF = (size_t)N * NF;

    _Float16* xf = (_Float16*)d_out;
    _Float16* yf = xf + NNF;
    float* ox = (float*)d_out;
    float* oy = ox + NNF;

    int* sb    = (int*)((char*)d_out + 4 * NNF);
    int* deg   = sb;
    int* loc   = sb + N;
    int* rowp  = sb + 2 * N;
    int* cur   = sb + 3 * N;
    int* parts = sb + 4 * N;
    int* ord   = sb + 4 * N + 64;

    float* conv_x = (float*)d_ws;
    float* conv_y = conv_x + NNF;

    const int NB = (N + 2047) / 2048;
    const int nodeTiles = (N + 63) / 64;
    const int nGroups = (N + 15) / 16;

    hipMemsetAsync(deg, 0, (size_t)N * sizeof(int), stream);

    proj_mfma_kernel<<<dim3(1024, 2), 256, 0, stream>>>(
        x, y, W_in2f, W_in2f_y, xf, yf, conv_y, N, nodeTiles);

    hist1_kernel<<<1024, 256, 0, stream>>>(idx_i, deg, E);
    scanA1_kernel<<<NB, 256, 0, stream>>>(deg, loc, parts, N);
    scanB1_kernel<<<1, 64, 0, stream>>>(parts, NB);
    scanC1_kernel<<<128, 256, 0, stream>>>(loc, parts, rowp, cur, N);
    scatter1_kernel<<<1024, 256, 0, stream>>>(idx_i, cur, ord, E);

    edge_hybrid_kernel<<<2048, 256, 0, stream>>>(
        f_ij, rcut, idx_i, idx_j, Wf1, bf1, Wf2, bf2, xf, yf,
        ord, rowp, conv_x, conv_y, N, E, nGroups);

    out_fused_kernel<<<dim3(1024, 2), 256, 0, stream>>>(
        conv_x, conv_y, Wx1, Wy1, bx1, by1, Wx2, Wy2, bx2, by2,
        ox, oy, N, nodeTiles);
}

// Round 19
// 729.545 us; speedup vs baseline: 1.0450x; 1.0113x over previous
//
#include <hip/hip_runtime.h>
#include <hip/hip_bf16.h>

#define NF 128
#define RBF 20

using short8 = __attribute__((ext_vector_type(8))) short;
using half8  = __attribute__((ext_vector_type(8))) _Float16;
using f32x4  = __attribute__((ext_vector_type(4))) float;

__device__ __forceinline__ float sspf(float v) {
    const float t = __expf(-fabsf(v));
    return fmaxf(v, 0.f) + __logf(1.f + t) - 0.69314718055994531f;
}
__device__ __forceinline__ unsigned short f2bf(float f) {
    union { float f; unsigned u; } v; v.f = f;
    unsigned r = v.u + 0x7fffu + ((v.u >> 16) & 1u);
    return (unsigned short)(r >> 16);
}
__device__ __forceinline__ float bf2f(unsigned short s) {
    union { unsigned u; float f; } v; v.u = ((unsigned)s) << 16;
    return v.f;
}

// ---------------------------------------------------------------------------
// Counting sort by idx_i only.
// ---------------------------------------------------------------------------
__global__ void hist1_kernel(const int* __restrict__ idx, int* __restrict__ deg, int E)
{
    for (int e = blockIdx.x * blockDim.x + threadIdx.x; e < E;
         e += gridDim.x * blockDim.x)
        atomicAdd(&deg[idx[e]], 1);
}

__global__ void scanA1_kernel(const int* __restrict__ deg, int* __restrict__ loc,
                              int* __restrict__ parts, int NN)
{
    const int tid = threadIdx.x;
    const int base = blockIdx.x * 2048;
    __shared__ int tsum[256];
    int v[8]; int s = 0;
    #pragma unroll
    for (int r = 0; r < 8; ++r) {
        const int idx = base + tid * 8 + r;
        v[r] = (idx < NN) ? deg[idx] : 0;
        s += v[r];
    }
    tsum[tid] = s;
    __syncthreads();
    #pragma unroll
    for (int d = 1; d < 256; d <<= 1) {
        const int add = (tid >= d) ? tsum[tid - d] : 0;
        __syncthreads();
        tsum[tid] += add;
        __syncthreads();
    }
    int run = tsum[tid] - s;
    #pragma unroll
    for (int r = 0; r < 8; ++r) {
        const int idx = base + tid * 8 + r;
        if (idx < NN) loc[idx] = run;
        run += v[r];
    }
    if (tid == 0) parts[blockIdx.x] = tsum[255];
}

__global__ void scanB1_kernel(int* __restrict__ parts, int NB)
{
    __shared__ int p[64];
    const int t = threadIdx.x;
    p[t] = (t < NB) ? parts[t] : 0;
    __syncthreads();
    #pragma unroll
    for (int d = 1; d < 64; d <<= 1) {
        const int add = (t >= d) ? p[t - d] : 0;
        __syncthreads();
        p[t] += add;
        __syncthreads();
    }
    parts[t] = (t > 0) ? p[t - 1] : 0;
}

__global__ void scanC1_kernel(const int* __restrict__ loc, const int* __restrict__ parts,
                              int* __restrict__ rowp, int* __restrict__ cur, int NN)
{
    for (int i = blockIdx.x * blockDim.x + threadIdx.x; i < NN;
         i += gridDim.x * blockDim.x) {
        const int v = loc[i] + parts[i >> 11];
        rowp[i] = v;
        cur[i]  = v;
    }
}

__global__ void scatter1_kernel(const int* __restrict__ idx, int* __restrict__ cur,
                                int* __restrict__ ord, int E)
{
    for (int e = blockIdx.x * blockDim.x + threadIdx.x; e < E;
         e += gridDim.x * blockDim.x) {
        const int p = atomicAdd(&cur[idx[e]], 1);
        ord[p] = e;
    }
}

// ---------------------------------------------------------------------------
// Hybrid edge kernel: 256 threads (4 waves), ONE 16-node group per block
// (exact grid -> HW scheduler load-balances; no persistent-loop quantization).
// selector-MFMA conv_x (plain stores) + halved fp32 atomics conv_y.
// ---------------------------------------------------------------------------
__global__ __launch_bounds__(256, 2)
void edge_hybrid_kernel(const float* __restrict__ f_ij,
                        const float* __restrict__ rcut,
                        const int* __restrict__ idx_i,
                        const int* __restrict__ idx_j,
                        const float* __restrict__ Wf1,
                        const float* __restrict__ bf1,
                        const float* __restrict__ Wf2,
                        const float* __restrict__ bf2v,
                        const _Float16* __restrict__ xf,
                        const _Float16* __restrict__ yf,
                        const int* __restrict__ ord,
                        const int* __restrict__ rowp,
                        float* __restrict__ conv_x,
                        float* __restrict__ conv_y,
                        int NN, int E)
{
    const int tid = threadIdx.x;
    const int l = tid & 63, w = tid >> 6;      // 4 waves
    const int lr = l & 15, lk = l >> 4;
    const int wcol0 = w * 32;                  // wave's 32-col slice

    __shared__ _Float16 M_s[32 * 137];         // 8.7 KB; first 32*40 aliases f-staging
    __shared__ _Float16 Ash[32 * 136];         // 8.5 KB: h (XOR swz) then g
    __shared__ _Float16 xown[16 * 136];        // 4.3 KB
    __shared__ int ni_s[32];
    __shared__ int jo_s[32];
    __shared__ float rc_s[32];

    _Float16* fst = M_s;                       // f staging, stride 40

    half8 b1fr[2];
    #pragma unroll
    for (int cb = 0; cb < 2; ++cb) {
        const int col = wcol0 + cb * 16 + lr;
        #pragma unroll
        for (int j = 0; j < 8; ++j) {
            const int k = lk * 8 + j;
            b1fr[cb][j] = (k < RBF) ? (_Float16)Wf1[k * NF + col] : (_Float16)0.f;
        }
    }
    half8 b2fr[4][2];
    #pragma unroll
    for (int kb = 0; kb < 4; ++kb)
        #pragma unroll
        for (int cb = 0; cb < 2; ++cb) {
            const int col = wcol0 + cb * 16 + lr;
            #pragma unroll
            for (int j = 0; j < 8; ++j)
                b2fr[kb][cb][j] = (_Float16)Wf2[(size_t)(kb * 32 + lk * 8 + j) * NF + col];
        }
    const float b1c[2] = { bf1[wcol0 + lr], bf1[wcol0 + 16 + lr] };
    const float b2c[2] = { bf2v[wcol0 + lr], bf2v[wcol0 + 16 + lr] };

    const int n0 = blockIdx.x * 16;
    const int eb = rowp[n0];
    const int ee = (n0 + 16 < NN) ? rowp[n0 + 16] : E;
    const int nt = (ee - eb + 31) >> 5;

    // stage own xf rows [n0, n0+16): 1024 uints, stride 136
    #pragma unroll
    for (int u = 0; u < 4; ++u) {
        const int tt = u * 256 + tid;
        const int row = tt >> 6, cp = tt & 63;
        unsigned v = 0;
        if (n0 + row < NN)
            v = reinterpret_cast<const unsigned*>(xf)[(size_t)(n0 + row) * 64 + cp];
        *reinterpret_cast<unsigned*>(&xown[row * 136 + cp * 2]) = v;
    }

    f32x4 accS[2] = {};   // 16 nodes x (2 col-blocks of 16)

    for (int t = 0; t < nt; ++t) {
        const int p0 = eb + t * 32;
        const int cnt = ee - p0;
        __syncthreads();               // prev-tile LDS readers done (covers xown)

        if (tid < 32) {
            const int p = p0 + tid;
            const bool val = p < ee;
            const int e = val ? ord[p] : 0;
            ni_s[tid] = val ? idx_i[e] : -1;
            jo_s[tid] = val ? idx_j[e] * NF : 0;
            rc_s[tid] = val ? rcut[e] : 0.f;
        }
        // stage f tile: 32 rows x 32 k (padded) = 1024 elems / 256 thr
        #pragma unroll
        for (int s4 = 0; s4 < 4; ++s4) {
            const int tt = s4 * 256 + tid;
            const int row = tt >> 5, k = tt & 31;
            const int p = p0 + row;
            float v = 0.f;
            if (k < RBF && p < ee) v = f_ij[(size_t)ord[p] * RBF + k];
            fst[row * 40 + k] = (_Float16)v;
        }
        __syncthreads();

        // phase 1: h = ssp(f @ W1 + b1) -> Ash (XOR swz, stride 136)
        f32x4 acc1[2][2] = {};
        #pragma unroll
        for (int rb = 0; rb < 2; ++rb) {
            const half8 a = *reinterpret_cast<const half8*>(
                &fst[(rb * 16 + lr) * 40 + lk * 8]);
            #pragma unroll
            for (int cb = 0; cb < 2; ++cb)
                acc1[rb][cb] = __builtin_amdgcn_mfma_f32_16x16x32_f16(
                    a, b1fr[cb], acc1[rb][cb], 0, 0, 0);
        }
        #pragma unroll
        for (int rb = 0; rb < 2; ++rb)
            #pragma unroll
            for (int cb = 0; cb < 2; ++cb) {
                const int col = wcol0 + cb * 16 + lr;
                #pragma unroll
                for (int q = 0; q < 4; ++q) {
                    const int e = rb * 16 + lk * 4 + q;
                    const float hv = sspf(acc1[rb][cb][q] + b1c[cb]);
                    Ash[e * 136 + (col ^ ((e & 7) << 3))] = (_Float16)hv;
                }
            }
        __syncthreads();

        // EARLY: issue g gather loads (hide under phase-2 MFMA)
        unsigned gr[8];
        #pragma unroll
        for (int u = 0; u < 8; ++u) {
            const int tt = u * 256 + tid;
            const int slot = tt >> 6, cp = tt & 63;
            gr[u] = reinterpret_cast<const unsigned*>(yf)[(jo_s[slot] >> 1) + cp];
        }

        // phase 2: wij = h @ W2
        f32x4 acc2[2][2] = {};
        #pragma unroll
        for (int rb = 0; rb < 2; ++rb) {
            half8 a[4];
            #pragma unroll
            for (int kb = 0; kb < 4; ++kb) {
                const int e  = rb * 16 + lr;
                const int k0 = kb * 32 + lk * 8;
                a[kb] = *reinterpret_cast<const half8*>(
                    &Ash[e * 136 + (k0 ^ ((e & 7) << 3))]);
            }
            #pragma unroll
            for (int cb = 0; cb < 2; ++cb)
                #pragma unroll
                for (int kb = 0; kb < 4; ++kb)
                    acc2[rb][cb] = __builtin_amdgcn_mfma_f32_16x16x32_f16(
                        a[kb], b2fr[kb][cb], acc2[rb][cb], 0, 0, 0);
        }
        __syncthreads();            // h reads done -> Ash reusable for g

        // g ds_writes into Ash (stride 136) from prefetched registers
        #pragma unroll
        for (int u = 0; u < 8; ++u) {
            const int tt = u * 256 + tid;
            const int slot = tt >> 6, cp = tt & 63;
            *reinterpret_cast<unsigned*>(&Ash[slot * 136 + cp * 2]) = gr[u];
        }
        __syncthreads();

        // per-thread: M = wv*g -> M_s (f dead) + y-side atomics (valid slots)
        #pragma unroll
        for (int rb = 0; rb < 2; ++rb)
            #pragma unroll
            for (int cb = 0; cb < 2; ++cb) {
                const int col = wcol0 + cb * 16 + lr;
                #pragma unroll
                for (int q = 0; q < 4; ++q) {
                    const int e = rb * 16 + lk * 4 + q;
                    const float wv = (acc2[rb][cb][q] + b2c[cb]) * rc_s[e];
                    const float g  = (float)Ash[e * 136 + col];
                    M_s[e * 137 + col] = (_Float16)(wv * g);
                    if (e < cnt) {
                        const int oi = ni_s[e] - n0;
                        const float xo = (float)xown[oi * 136 + col];
                        unsafeAtomicAdd(&conv_y[(size_t)jo_s[e] + col], xo * wv);
                    }
                }
            }
        __syncthreads();

        // phase 3: accS += S @ M  (selector one-hot, K=32 in one step)
        {
            half8 as;
            int nn[8];
            #pragma unroll
            for (int j = 0; j < 8; ++j) nn[j] = ni_s[lk * 8 + j];
            const int node = n0 + lr;
            #pragma unroll
            for (int j = 0; j < 8; ++j)
                as[j] = (nn[j] == node) ? (_Float16)1.f : (_Float16)0.f;
            #pragma unroll
            for (int cb = 0; cb < 2; ++cb) {
                const int col = wcol0 + cb * 16 + lr;
                half8 bm;
                #pragma unroll
                for (int j = 0; j < 8; ++j)
                    bm[j] = M_s[(lk * 8 + j) * 137 + col];
                accS[cb] = __builtin_amdgcn_mfma_f32_16x16x32_f16(
                    as, bm, accS[cb], 0, 0, 0);
            }
        }
    }

    // conv_x rows [n0, n0+16): written once, plain stores
    #pragma unroll
    for (int cb = 0; cb < 2; ++cb) {
        const int col = wcol0 + cb * 16 + lr;
        #pragma unroll
        for (int q = 0; q < 4; ++q) {
            const int n = n0 + lk * 4 + q;
            if (n < NN) conv_x[(size_t)n * NF + col] = accS[cb][q];
        }
    }
}

// ---------------------------------------------------------------------------
// Projection (exact grid, f16): out_f16 = in @ W (bias-free) + zero conv_y
// ---------------------------------------------------------------------------
__global__ __launch_bounds__(256, 2)
void proj_mfma_kernel(const float* in0, const float* in1,
                      const float* __restrict__ W0, const float* __restrict__ W1p,
                      _Float16* o0, _Float16* o1,
                      float* __restrict__ conv_y, int N)
{
    const float* in = blockIdx.y ? in1 : in0;
    const float* W  = blockIdx.y ? W1p : W0;
    _Float16* out   = blockIdx.y ? o1 : o0;

    const int tid = threadIdx.x;
    const int l = tid & 63, w = tid >> 6;
    const int lr = l & 15, lk = l >> 4;
    const int wcol0 = w * 32;

    __shared__ _Float16 Ahi[64 * NF];

    half8 bfr[4][2];
    #pragma unroll
    for (int kb = 0; kb < 4; ++kb)
        #pragma unroll
        for (int cb = 0; cb < 2; ++cb) {
            const int col = wcol0 + cb * 16 + lr;
            #pragma unroll
            for (int j = 0; j < 8; ++j)
                bfr[kb][cb][j] = (_Float16)W[(size_t)(kb * 32 + lk * 8 + j) * NF + col];
        }

    const int n0 = blockIdx.x * 64;
    #pragma unroll
    for (int s = 0; s < 32; ++s) {
        const int t = s * 256 + tid;
        const int row = t >> 7, cc = t & (NF - 1);
        const float v = (n0 + row < N) ? in[(size_t)(n0 + row) * NF + cc] : 0.f;
        Ahi[row * NF + (cc ^ ((row & 7) << 3))] = (_Float16)v;
    }
    {
        const float4 z = {0.f, 0.f, 0.f, 0.f};
        const int rbase = n0 + 32 * blockIdx.y;
        #pragma unroll
        for (int s = 0; s < 4; ++s) {
            const int t = s * 256 + tid;
            const int row = rbase + (t >> 5);
            if (row < N)
                *reinterpret_cast<float4*>(&conv_y[(size_t)row * NF + (t & 31) * 4]) = z;
        }
    }
    __syncthreads();

    f32x4 acc[4][2] = {};
    #pragma unroll
    for (int rb = 0; rb < 4; ++rb) {
        half8 a[4];
        #pragma unroll
        for (int kb = 0; kb < 4; ++kb) {
            const int e  = rb * 16 + lr;
            const int k0 = kb * 32 + lk * 8;
            a[kb] = *reinterpret_cast<const half8*>(&Ahi[e * NF + (k0 ^ ((e & 7) << 3))]);
        }
        #pragma unroll
        for (int cb = 0; cb < 2; ++cb)
            #pragma unroll
            for (int kb = 0; kb < 4; ++kb)
                acc[rb][cb] = __builtin_amdgcn_mfma_f32_16x16x32_f16(
                    a[kb], bfr[kb][cb], acc[rb][cb], 0, 0, 0);
    }

    #pragma unroll
    for (int rb = 0; rb < 4; ++rb)
        #pragma unroll
        for (int cb = 0; cb < 2; ++cb) {
            const int col = wcol0 + cb * 16 + lr;
            #pragma unroll
            for (int q = 0; q < 4; ++q) {
                const int n = n0 + rb * 16 + lk * 4 + q;
                if (n < N) out[(size_t)n * NF + col] = (_Float16)acc[rb][cb][q];
            }
        }
}

// ---------------------------------------------------------------------------
// Fused output MLP (exact grid): out = ssp(conv @ W1 + b1) @ W2 + b2
// split-bf16 (hi/lo) A for near-fp32 precision.
// ---------------------------------------------------------------------------
__global__ __launch_bounds__(256, 2)
void out_fused_kernel(const float* conv0, const float* conv1,
                      const float* __restrict__ W10, const float* __restrict__ W11,
                      const float* __restrict__ b10, const float* __restrict__ b11,
                      const float* __restrict__ W20, const float* __restrict__ W21,
                      const float* __restrict__ b20, const float* __restrict__ b21,
                      float* o0, float* o1, int N)
{
    const float* in = blockIdx.y ? conv1 : conv0;
    const float* W1 = blockIdx.y ? W11 : W10;
    const float* b1 = blockIdx.y ? b11 : b10;
    const float* W2 = blockIdx.y ? W21 : W20;
    const float* b2 = blockIdx.y ? b21 : b20;
    float* out      = blockIdx.y ? o1  : o0;

    const int tid = threadIdx.x;
    const int l = tid & 63, w = tid >> 6;
    const int lr = l & 15, lk = l >> 4;
    const int wcol0 = w * 32;

    __shared__ unsigned short Ahi[64 * NF];
    __shared__ unsigned short Alo[64 * NF];

    short8 w1fr[4][2], w2fr[4][2];
    #pragma unroll
    for (int kb = 0; kb < 4; ++kb)
        #pragma unroll
        for (int cb = 0; cb < 2; ++cb) {
            const int col = wcol0 + cb * 16 + lr;
            #pragma unroll
            for (int j = 0; j < 8; ++j) {
                const size_t kk = (size_t)(kb * 32 + lk * 8 + j) * NF + col;
                w1fr[kb][cb][j] = (short)f2bf(W1[kk]);
                w2fr[kb][cb][j] = (short)f2bf(W2[kk]);
            }
        }
    const float b1c0 = b1[wcol0 + lr], b1c1 = b1[wcol0 + 16 + lr];
    const float b2c0 = b2[wcol0 + lr], b2c1 = b2[wcol0 + 16 + lr];

    const int n0 = blockIdx.x * 64;
    #pragma unroll
    for (int s = 0; s < 32; ++s) {
        const int t = s * 256 + tid;
        const int row = t >> 7, cc = t & (NF - 1);
        const float v = (n0 + row < N) ? in[(size_t)(n0 + row) * NF + cc] : 0.f;
        const unsigned short hi = f2bf(v);
        const int idx = row * NF + (cc ^ ((row & 7) << 3));
        Ahi[idx] = hi;
        Alo[idx] = f2bf(v - bf2f(hi));
    }
    __syncthreads();

    f32x4 acc1[4][2] = {};
    #pragma unroll
    for (int rb = 0; rb < 4; ++rb) {
        short8 ah[4], al[4];
        #pragma unroll
        for (int kb = 0; kb < 4; ++kb) {
            const int e  = rb * 16 + lr;
            const int k0 = kb * 32 + lk * 8;
            const int idx = e * NF + (k0 ^ ((e & 7) << 3));
            ah[kb] = *reinterpret_cast<const short8*>(&Ahi[idx]);
            al[kb] = *reinterpret_cast<const short8*>(&Alo[idx]);
        }
        #pragma unroll
        for (int cb = 0; cb < 2; ++cb)
            #pragma unroll
            for (int kb = 0; kb < 4; ++kb) {
                acc1[rb][cb] = __builtin_amdgcn_mfma_f32_16x16x32_bf16(
                    ah[kb], w1fr[kb][cb], acc1[rb][cb], 0, 0, 0);
                acc1[rb][cb] = __builtin_amdgcn_mfma_f32_16x16x32_bf16(
                    al[kb], w1fr[kb][cb], acc1[rb][cb], 0, 0, 0);
            }
    }
    __syncthreads();

    #pragma unroll
    for (int rb = 0; rb < 4; ++rb)
        #pragma unroll
        for (int cb = 0; cb < 2; ++cb) {
            const int col = wcol0 + cb * 16 + lr;
            #pragma unroll
            for (int q = 0; q < 4; ++q) {
                const int e = rb * 16 + lk * 4 + q;
                const float hv = sspf(acc1[rb][cb][q] + (cb ? b1c1 : b1c0));
                const unsigned short hi = f2bf(hv);
                const int idx = e * NF + (col ^ ((e & 7) << 3));
                Ahi[idx] = hi;
                Alo[idx] = f2bf(hv - bf2f(hi));
            }
        }
    __syncthreads();

    f32x4 acc2[4][2] = {};
    #pragma unroll
    for (int rb = 0; rb < 4; ++rb) {
        short8 ah[4], al[4];
        #pragma unroll
        for (int kb = 0; kb < 4; ++kb) {
            const int e  = rb * 16 + lr;
            const int k0 = kb * 32 + lk * 8;
            const int idx = e * NF + (k0 ^ ((e & 7) << 3));
            ah[kb] = *reinterpret_cast<const short8*>(&Ahi[idx]);
            al[kb] = *reinterpret_cast<const short8*>(&Alo[idx]);
        }
        #pragma unroll
        for (int cb = 0; cb < 2; ++cb)
            #pragma unroll
            for (int kb = 0; kb < 4; ++kb) {
                acc2[rb][cb] = __builtin_amdgcn_mfma_f32_16x16x32_bf16(
                    ah[kb], w2fr[kb][cb], acc2[rb][cb], 0, 0, 0);
                acc2[rb][cb] = __builtin_amdgcn_mfma_f32_16x16x32_bf16(
                    al[kb], w2fr[kb][cb], acc2[rb][cb], 0, 0, 0);
            }
    }

    #pragma unroll
    for (int rb = 0; rb < 4; ++rb)
        #pragma unroll
        for (int cb = 0; cb < 2; ++cb) {
            const int col = wcol0 + cb * 16 + lr;
            #pragma unroll
            for (int q = 0; q < 4; ++q) {
                const int n = n0 + rb * 16 + lk * 4 + q;
                if (n < N)
                    out[(size_t)n * NF + col] = acc2[rb][cb][q] + (cb ? b2c1 : b2c0);
            }
        }
}

extern "C" void kernel_launch(void* const* d_in, const int* in_sizes, int n_in,
                              void* d_out, int out_size, void* d_ws, size_t ws_size,
                              hipStream_t stream)
{
    const float* x    = (const float*)d_in[0];
    const float* y    = (const float*)d_in[1];
    const float* f_ij = (const float*)d_in[2];
    const float* rcut = (const float*)d_in[3];
    const int* idx_i  = (const int*)d_in[4];
    const int* idx_j  = (const int*)d_in[5];
    const float* W_in2f   = (const float*)d_in[6];
    const float* W_in2f_y = (const float*)d_in[7];
    const float* Wf1 = (const float*)d_in[8];
    const float* bf1 = (const float*)d_in[9];
    const float* Wf2 = (const float*)d_in[10];
    const float* bf2 = (const float*)d_in[11];
    const float* Wx1 = (const float*)d_in[12];
    const float* bx1 = (const float*)d_in[13];
    const float* Wx2 = (const float*)d_in[14];
    const float* bx2 = (const float*)d_in[15];
    const float* Wy1 = (const float*)d_in[16];
    const float* by1 = (const float*)d_in[17];
    const float* Wy2 = (const float*)d_in[18];
    const float* by2 = (const float*)d_in[19];

    const int N = in_sizes[0] / NF;
    const int E = in_sizes[4];
    const size_t NNF = (size_t)N * NF;

    _Float16* xf = (_Float16*)d_out;
    _Float16* yf = xf + NNF;
    float* ox = (float*)d_out;
    float* oy = ox + NNF;

    int* sb    = (int*)((char*)d_out + 4 * NNF);
    int* deg   = sb;
    int* loc   = sb + N;
    int* rowp  = sb + 2 * N;
    int* cur   = sb + 3 * N;
    int* parts = sb + 4 * N;
    int* ord   = sb + 4 * N + 64;

    float* conv_x = (float*)d_ws;
    float* conv_y = conv_x + NNF;

    const int NB = (N + 2047) / 2048;
    const int nodeTiles = (N + 63) / 64;
    const int nGroups = (N + 15) / 16;

    hipMemsetAsync(deg, 0, (size_t)N * sizeof(int), stream);

    proj_mfma_kernel<<<dim3(nodeTiles, 2), 256, 0, stream>>>(
        x, y, W_in2f, W_in2f_y, xf, yf, conv_y, N);

    hist1_kernel<<<1024, 256, 0, stream>>>(idx_i, deg, E);
    scanA1_kernel<<<NB, 256, 0, stream>>>(deg, loc, parts, N);
    scanB1_kernel<<<1, 64, 0, stream>>>(parts, NB);
    scanC1_kernel<<<128, 256, 0, stream>>>(loc, parts, rowp, cur, N);
    scatter1_kernel<<<1024, 256, 0, stream>>>(idx_i, cur, ord, E);

    edge_hybrid_kernel<<<nGroups, 256, 0, stream>>>(
        f_ij, rcut, idx_i, idx_j, Wf1, bf1, Wf2, bf2, xf, yf,
        ord, rowp, conv_x, conv_y, N, E);

    out_fused_kernel<<<dim3(nodeTiles, 2), 256, 0, stream>>>(
        conv_x, conv_y, Wx1, Wy1, bx1, by1, Wx2, Wy2, bx2, by2,
        ox, oy, N);
}

// Round 20
// 647.597 us; speedup vs baseline: 1.1773x; 1.1265x over previous
//
#include <hip/hip_runtime.h>
#include <hip/hip_bf16.h>

#define NF 128
#define RBF 20

using short8 = __attribute__((ext_vector_type(8))) short;
using half8  = __attribute__((ext_vector_type(8))) _Float16;
using f32x4  = __attribute__((ext_vector_type(4))) float;

__device__ __forceinline__ float sspf(float v) {
    const float t = __expf(-fabsf(v));
    return fmaxf(v, 0.f) + __logf(1.f + t) - 0.69314718055994531f;
}
__device__ __forceinline__ unsigned short f2bf(float f) {
    union { float f; unsigned u; } v; v.f = f;
    unsigned r = v.u + 0x7fffu + ((v.u >> 16) & 1u);
    return (unsigned short)(r >> 16);
}
__device__ __forceinline__ float bf2f(unsigned short s) {
    union { unsigned u; float f; } v; v.u = ((unsigned)s) << 16;
    return v.f;
}

// ---------------------------------------------------------------------------
// Counting sort by idx_i; sorted meta (ni/jo/rc) materialized at scatter.
// ---------------------------------------------------------------------------
__global__ void hist1_kernel(const int* __restrict__ idx, int* __restrict__ deg, int E)
{
    for (int e = blockIdx.x * blockDim.x + threadIdx.x; e < E;
         e += gridDim.x * blockDim.x)
        atomicAdd(&deg[idx[e]], 1);
}

__global__ void scanA1_kernel(const int* __restrict__ deg, int* __restrict__ loc,
                              int* __restrict__ parts, int NN)
{
    const int tid = threadIdx.x;
    const int base = blockIdx.x * 2048;
    __shared__ int tsum[256];
    int v[8]; int s = 0;
    #pragma unroll
    for (int r = 0; r < 8; ++r) {
        const int idx = base + tid * 8 + r;
        v[r] = (idx < NN) ? deg[idx] : 0;
        s += v[r];
    }
    tsum[tid] = s;
    __syncthreads();
    #pragma unroll
    for (int d = 1; d < 256; d <<= 1) {
        const int add = (tid >= d) ? tsum[tid - d] : 0;
        __syncthreads();
        tsum[tid] += add;
        __syncthreads();
    }
    int run = tsum[tid] - s;
    #pragma unroll
    for (int r = 0; r < 8; ++r) {
        const int idx = base + tid * 8 + r;
        if (idx < NN) loc[idx] = run;
        run += v[r];
    }
    if (tid == 0) parts[blockIdx.x] = tsum[255];
}

__global__ void scanB1_kernel(int* __restrict__ parts, int NB)
{
    __shared__ int p[64];
    const int t = threadIdx.x;
    p[t] = (t < NB) ? parts[t] : 0;
    __syncthreads();
    #pragma unroll
    for (int d = 1; d < 64; d <<= 1) {
        const int add = (t >= d) ? p[t - d] : 0;
        __syncthreads();
        p[t] += add;
        __syncthreads();
    }
    parts[t] = (t > 0) ? p[t - 1] : 0;
}

__global__ void scanC1_kernel(const int* __restrict__ loc, const int* __restrict__ parts,
                              int* __restrict__ rowp, int* __restrict__ cur, int NN)
{
    for (int i = blockIdx.x * blockDim.x + threadIdx.x; i < NN;
         i += gridDim.x * blockDim.x) {
        const int v = loc[i] + parts[i >> 11];
        rowp[i] = v;
        cur[i]  = v;
    }
}

__global__ void scatter1_kernel(const int* __restrict__ idx_i, const int* __restrict__ idx_j,
                                const float* __restrict__ rcut,
                                int* __restrict__ cur, int* __restrict__ ord,
                                int* __restrict__ nis, int* __restrict__ jos,
                                float* __restrict__ rcs, int E)
{
    for (int e = blockIdx.x * blockDim.x + threadIdx.x; e < E;
         e += gridDim.x * blockDim.x) {
        const int key = idx_i[e];
        const int p = atomicAdd(&cur[key], 1);
        ord[p] = e;
        nis[p] = key;
        jos[p] = idx_j[e] * NF;
        rcs[p] = rcut[e];
    }
}

// materialize f in sorted order, f16, K padded to 32 (64 B/row, coalesced)
__global__ void fsort_kernel(const float* __restrict__ f_ij,
                             const int* __restrict__ ord,
                             _Float16* __restrict__ f16s, int E)
{
    for (int p = blockIdx.x * blockDim.x + threadIdx.x; p < E;
         p += gridDim.x * blockDim.x) {
        const int e = ord[p];
        const float* src = f_ij + (size_t)e * RBF;
        _Float16* dst = f16s + (size_t)p * 32;
        #pragma unroll
        for (int k4 = 0; k4 < 5; ++k4) {
            const float4 v = *reinterpret_cast<const float4*>(src + k4 * 4);
            dst[k4 * 4 + 0] = (_Float16)v.x;
            dst[k4 * 4 + 1] = (_Float16)v.y;
            dst[k4 * 4 + 2] = (_Float16)v.z;
            dst[k4 * 4 + 3] = (_Float16)v.w;
        }
        #pragma unroll
        for (int k = RBF; k < 32; ++k) dst[k] = (_Float16)0.f;
    }
}

// ---------------------------------------------------------------------------
// Hybrid edge kernel: 256 threads (4 waves), ONE 16-node group per block.
// ALL tile staging is LINEAR (sorted f16s/nis/jos/rcs) — no indirection chain.
// selector-MFMA conv_x (plain stores) + halved fp32 atomics conv_y.
// ---------------------------------------------------------------------------
__global__ __launch_bounds__(256, 2)
void edge_hybrid_kernel(const _Float16* __restrict__ f16s,
                        const int* __restrict__ nis,
                        const int* __restrict__ jos,
                        const float* __restrict__ rcs,
                        const float* __restrict__ Wf1,
                        const float* __restrict__ bf1,
                        const float* __restrict__ Wf2,
                        const float* __restrict__ bf2v,
                        const _Float16* __restrict__ xf,
                        const _Float16* __restrict__ yf,
                        const int* __restrict__ rowp,
                        float* __restrict__ conv_x,
                        float* __restrict__ conv_y,
                        int NN, int E)
{
    const int tid = threadIdx.x;
    const int l = tid & 63, w = tid >> 6;      // 4 waves
    const int lr = l & 15, lk = l >> 4;
    const int wcol0 = w * 32;

    __shared__ _Float16 M_s[32 * 137];         // 8.7 KB; first 32*32 aliases f tile
    __shared__ _Float16 Ash[32 * 136];         // 8.5 KB: h (XOR swz) then g
    __shared__ _Float16 xown[16 * 136];        // 4.3 KB
    __shared__ int ni_s[32];
    __shared__ int jo_s[32];
    __shared__ float rc_s[32];

    _Float16* fst = M_s;                       // f tile, stride 32 halves (64 B rows)

    half8 b1fr[2];
    #pragma unroll
    for (int cb = 0; cb < 2; ++cb) {
        const int col = wcol0 + cb * 16 + lr;
        #pragma unroll
        for (int j = 0; j < 8; ++j) {
            const int k = lk * 8 + j;
            b1fr[cb][j] = (k < RBF) ? (_Float16)Wf1[k * NF + col] : (_Float16)0.f;
        }
    }
    half8 b2fr[4][2];
    #pragma unroll
    for (int kb = 0; kb < 4; ++kb)
        #pragma unroll
        for (int cb = 0; cb < 2; ++cb) {
            const int col = wcol0 + cb * 16 + lr;
            #pragma unroll
            for (int j = 0; j < 8; ++j)
                b2fr[kb][cb][j] = (_Float16)Wf2[(size_t)(kb * 32 + lk * 8 + j) * NF + col];
        }
    const float b1c[2] = { bf1[wcol0 + lr], bf1[wcol0 + 16 + lr] };
    const float b2c[2] = { bf2v[wcol0 + lr], bf2v[wcol0 + 16 + lr] };

    const int n0 = blockIdx.x * 16;
    const int eb = rowp[n0];
    const int ee = (n0 + 16 < NN) ? rowp[n0 + 16] : E;
    const int nt = (ee - eb + 31) >> 5;

    // stage own xf rows [n0, n0+16): 1024 uints, stride 136
    #pragma unroll
    for (int u = 0; u < 4; ++u) {
        const int tt = u * 256 + tid;
        const int row = tt >> 6, cp = tt & 63;
        unsigned v = 0;
        if (n0 + row < NN)
            v = reinterpret_cast<const unsigned*>(xf)[(size_t)(n0 + row) * 64 + cp];
        *reinterpret_cast<unsigned*>(&xown[row * 136 + cp * 2]) = v;
    }

    f32x4 accS[2] = {};

    for (int t = 0; t < nt; ++t) {
        const int p0 = eb + t * 32;
        const int cnt = ee - p0;
        __syncthreads();               // prev-tile LDS readers done (covers xown)

        // meta: LINEAR loads from sorted arrays (no indirection)
        if (tid < 32) {
            const int p = p0 + tid;
            const bool val = p < ee;
            ni_s[tid] = val ? nis[p] : -1;
            jo_s[tid] = val ? jos[p] : 0;
            rc_s[tid] = val ? rcs[p] : 0.f;
        }
        // f tile: 32 rows x 16 uints = 512 uints, fully LINEAR & coalesced
        {
            const unsigned* src = reinterpret_cast<const unsigned*>(f16s);
            unsigned* dst = reinterpret_cast<unsigned*>(fst);
            #pragma unroll
            for (int s2 = 0; s2 < 2; ++s2) {
                const int tt = s2 * 256 + tid;
                int p = p0 + (tt >> 4);
                if (p >= E) p = E - 1;          // clamp (rc=0 kills contribution)
                dst[tt] = src[(size_t)p * 16 + (tt & 15)];
            }
        }
        __syncthreads();

        // phase 1: h = ssp(f @ W1 + b1) -> Ash (XOR swz, stride 136)
        f32x4 acc1[2][2] = {};
        #pragma unroll
        for (int rb = 0; rb < 2; ++rb) {
            const half8 a = *reinterpret_cast<const half8*>(
                &fst[(rb * 16 + lr) * 32 + lk * 8]);
            #pragma unroll
            for (int cb = 0; cb < 2; ++cb)
                acc1[rb][cb] = __builtin_amdgcn_mfma_f32_16x16x32_f16(
                    a, b1fr[cb], acc1[rb][cb], 0, 0, 0);
        }
        #pragma unroll
        for (int rb = 0; rb < 2; ++rb)
            #pragma unroll
            for (int cb = 0; cb < 2; ++cb) {
                const int col = wcol0 + cb * 16 + lr;
                #pragma unroll
                for (int q = 0; q < 4; ++q) {
                    const int e = rb * 16 + lk * 4 + q;
                    const float hv = sspf(acc1[rb][cb][q] + b1c[cb]);
                    Ash[e * 136 + (col ^ ((e & 7) << 3))] = (_Float16)hv;
                }
            }
        __syncthreads();

        // EARLY: issue g gather loads (hide under phase-2 MFMA)
        unsigned gr[8];
        #pragma unroll
        for (int u = 0; u < 8; ++u) {
            const int tt = u * 256 + tid;
            const int slot = tt >> 6, cp = tt & 63;
            gr[u] = reinterpret_cast<const unsigned*>(yf)[(jo_s[slot] >> 1) + cp];
        }

        // phase 2: wij = h @ W2
        f32x4 acc2[2][2] = {};
        #pragma unroll
        for (int rb = 0; rb < 2; ++rb) {
            half8 a[4];
            #pragma unroll
            for (int kb = 0; kb < 4; ++kb) {
                const int e  = rb * 16 + lr;
                const int k0 = kb * 32 + lk * 8;
                a[kb] = *reinterpret_cast<const half8*>(
                    &Ash[e * 136 + (k0 ^ ((e & 7) << 3))]);
            }
            #pragma unroll
            for (int cb = 0; cb < 2; ++cb)
                #pragma unroll
                for (int kb = 0; kb < 4; ++kb)
                    acc2[rb][cb] = __builtin_amdgcn_mfma_f32_16x16x32_f16(
                        a[kb], b2fr[kb][cb], acc2[rb][cb], 0, 0, 0);
        }
        __syncthreads();            // h reads done -> Ash reusable for g

        // g ds_writes into Ash (stride 136) from prefetched registers
        #pragma unroll
        for (int u = 0; u < 8; ++u) {
            const int tt = u * 256 + tid;
            const int slot = tt >> 6, cp = tt & 63;
            *reinterpret_cast<unsigned*>(&Ash[slot * 136 + cp * 2]) = gr[u];
        }
        __syncthreads();

        // per-thread: M = wv*g -> M_s + y-side atomics (valid slots only)
        #pragma unroll
        for (int rb = 0; rb < 2; ++rb)
            #pragma unroll
            for (int cb = 0; cb < 2; ++cb) {
                const int col = wcol0 + cb * 16 + lr;
                #pragma unroll
                for (int q = 0; q < 4; ++q) {
                    const int e = rb * 16 + lk * 4 + q;
                    const float wv = (acc2[rb][cb][q] + b2c[cb]) * rc_s[e];
                    const float g  = (float)Ash[e * 136 + col];
                    M_s[e * 137 + col] = (_Float16)(wv * g);
                    if (e < cnt) {
                        const int oi = ni_s[e] - n0;
                        const float xo = (float)xown[oi * 136 + col];
                        unsafeAtomicAdd(&conv_y[(size_t)jo_s[e] + col], xo * wv);
                    }
                }
            }
        __syncthreads();

        // phase 3: accS += S @ M  (selector one-hot, K=32)
        {
            half8 as;
            int nn[8];
            #pragma unroll
            for (int j = 0; j < 8; ++j) nn[j] = ni_s[lk * 8 + j];
            const int node = n0 + lr;
            #pragma unroll
            for (int j = 0; j < 8; ++j)
                as[j] = (nn[j] == node) ? (_Float16)1.f : (_Float16)0.f;
            #pragma unroll
            for (int cb = 0; cb < 2; ++cb) {
                const int col = wcol0 + cb * 16 + lr;
                half8 bm;
                #pragma unroll
                for (int j = 0; j < 8; ++j)
                    bm[j] = M_s[(lk * 8 + j) * 137 + col];
                accS[cb] = __builtin_amdgcn_mfma_f32_16x16x32_f16(
                    as, bm, accS[cb], 0, 0, 0);
            }
        }
    }

    // conv_x rows [n0, n0+16): written once, plain stores
    #pragma unroll
    for (int cb = 0; cb < 2; ++cb) {
        const int col = wcol0 + cb * 16 + lr;
        #pragma unroll
        for (int q = 0; q < 4; ++q) {
            const int n = n0 + lk * 4 + q;
            if (n < NN) conv_x[(size_t)n * NF + col] = accS[cb][q];
        }
    }
}

// ---------------------------------------------------------------------------
// Projection (exact grid, f16): out_f16 = in @ W (bias-free) + zero conv_y
// ---------------------------------------------------------------------------
__global__ __launch_bounds__(256, 2)
void proj_mfma_kernel(const float* in0, const float* in1,
                      const float* __restrict__ W0, const float* __restrict__ W1p,
                      _Float16* o0, _Float16* o1,
                      float* __restrict__ conv_y, int N)
{
    const float* in = blockIdx.y ? in1 : in0;
    const float* W  = blockIdx.y ? W1p : W0;
    _Float16* out   = blockIdx.y ? o1 : o0;

    const int tid = threadIdx.x;
    const int l = tid & 63, w = tid >> 6;
    const int lr = l & 15, lk = l >> 4;
    const int wcol0 = w * 32;

    __shared__ _Float16 Ahi[64 * NF];

    half8 bfr[4][2];
    #pragma unroll
    for (int kb = 0; kb < 4; ++kb)
        #pragma unroll
        for (int cb = 0; cb < 2; ++cb) {
            const int col = wcol0 + cb * 16 + lr;
            #pragma unroll
            for (int j = 0; j < 8; ++j)
                bfr[kb][cb][j] = (_Float16)W[(size_t)(kb * 32 + lk * 8 + j) * NF + col];
        }

    const int n0 = blockIdx.x * 64;
    #pragma unroll
    for (int s = 0; s < 32; ++s) {
        const int t = s * 256 + tid;
        const int row = t >> 7, cc = t & (NF - 1);
        const float v = (n0 + row < N) ? in[(size_t)(n0 + row) * NF + cc] : 0.f;
        Ahi[row * NF + (cc ^ ((row & 7) << 3))] = (_Float16)v;
    }
    {
        const float4 z = {0.f, 0.f, 0.f, 0.f};
        const int rbase = n0 + 32 * blockIdx.y;
        #pragma unroll
        for (int s = 0; s < 4; ++s) {
            const int t = s * 256 + tid;
            const int row = rbase + (t >> 5);
            if (row < N)
                *reinterpret_cast<float4*>(&conv_y[(size_t)row * NF + (t & 31) * 4]) = z;
        }
    }
    __syncthreads();

    f32x4 acc[4][2] = {};
    #pragma unroll
    for (int rb = 0; rb < 4; ++rb) {
        half8 a[4];
        #pragma unroll
        for (int kb = 0; kb < 4; ++kb) {
            const int e  = rb * 16 + lr;
            const int k0 = kb * 32 + lk * 8;
            a[kb] = *reinterpret_cast<const half8*>(&Ahi[e * NF + (k0 ^ ((e & 7) << 3))]);
        }
        #pragma unroll
        for (int cb = 0; cb < 2; ++cb)
            #pragma unroll
            for (int kb = 0; kb < 4; ++kb)
                acc[rb][cb] = __builtin_amdgcn_mfma_f32_16x16x32_f16(
                    a[kb], bfr[kb][cb], acc[rb][cb], 0, 0, 0);
    }

    #pragma unroll
    for (int rb = 0; rb < 4; ++rb)
        #pragma unroll
        for (int cb = 0; cb < 2; ++cb) {
            const int col = wcol0 + cb * 16 + lr;
            #pragma unroll
            for (int q = 0; q < 4; ++q) {
                const int n = n0 + rb * 16 + lk * 4 + q;
                if (n < N) out[(size_t)n * NF + col] = (_Float16)acc[rb][cb][q];
            }
        }
}

// ---------------------------------------------------------------------------
// Fused output MLP (exact grid): out = ssp(conv @ W1 + b1) @ W2 + b2
// split-bf16 (hi/lo) A for near-fp32 precision.
// ---------------------------------------------------------------------------
__global__ __launch_bounds__(256, 2)
void out_fused_kernel(const float* conv0, const float* conv1,
                      const float* __restrict__ W10, const float* __restrict__ W11,
                      const float* __restrict__ b10, const float* __restrict__ b11,
                      const float* __restrict__ W20, const float* __restrict__ W21,
                      const float* __restrict__ b20, const float* __restrict__ b21,
                      float* o0, float* o1, int N)
{
    const float* in = blockIdx.y ? conv1 : conv0;
    const float* W1 = blockIdx.y ? W11 : W10;
    const float* b1 = blockIdx.y ? b11 : b10;
    const float* W2 = blockIdx.y ? W21 : W20;
    const float* b2 = blockIdx.y ? b21 : b20;
    float* out      = blockIdx.y ? o1  : o0;

    const int tid = threadIdx.x;
    const int l = tid & 63, w = tid >> 6;
    const int lr = l & 15, lk = l >> 4;
    const int wcol0 = w * 32;

    __shared__ unsigned short Ahi[64 * NF];
    __shared__ unsigned short Alo[64 * NF];

    short8 w1fr[4][2], w2fr[4][2];
    #pragma unroll
    for (int kb = 0; kb < 4; ++kb)
        #pragma unroll
        for (int cb = 0; cb < 2; ++cb) {
            const int col = wcol0 + cb * 16 + lr;
            #pragma unroll
            for (int j = 0; j < 8; ++j) {
                const size_t kk = (size_t)(kb * 32 + lk * 8 + j) * NF + col;
                w1fr[kb][cb][j] = (short)f2bf(W1[kk]);
                w2fr[kb][cb][j] = (short)f2bf(W2[kk]);
            }
        }
    const float b1c0 = b1[wcol0 + lr], b1c1 = b1[wcol0 + 16 + lr];
    const float b2c0 = b2[wcol0 + lr], b2c1 = b2[wcol0 + 16 + lr];

    const int n0 = blockIdx.x * 64;
    #pragma unroll
    for (int s = 0; s < 32; ++s) {
        const int t = s * 256 + tid;
        const int row = t >> 7, cc = t & (NF - 1);
        const float v = (n0 + row < N) ? in[(size_t)(n0 + row) * NF + cc] : 0.f;
        const unsigned short hi = f2bf(v);
        const int idx = row * NF + (cc ^ ((row & 7) << 3));
        Ahi[idx] = hi;
        Alo[idx] = f2bf(v - bf2f(hi));
    }
    __syncthreads();

    f32x4 acc1[4][2] = {};
    #pragma unroll
    for (int rb = 0; rb < 4; ++rb) {
        short8 ah[4], al[4];
        #pragma unroll
        for (int kb = 0; kb < 4; ++kb) {
            const int e  = rb * 16 + lr;
            const int k0 = kb * 32 + lk * 8;
            const int idx = e * NF + (k0 ^ ((e & 7) << 3));
            ah[kb] = *reinterpret_cast<const short8*>(&Ahi[idx]);
            al[kb] = *reinterpret_cast<const short8*>(&Alo[idx]);
        }
        #pragma unroll
        for (int cb = 0; cb < 2; ++cb)
            #pragma unroll
            for (int kb = 0; kb < 4; ++kb) {
                acc1[rb][cb] = __builtin_amdgcn_mfma_f32_16x16x32_bf16(
                    ah[kb], w1fr[kb][cb], acc1[rb][cb], 0, 0, 0);
                acc1[rb][cb] = __builtin_amdgcn_mfma_f32_16x16x32_bf16(
                    al[kb], w1fr[kb][cb], acc1[rb][cb], 0, 0, 0);
            }
    }
    __syncthreads();

    #pragma unroll
    for (int rb = 0; rb < 4; ++rb)
        #pragma unroll
        for (int cb = 0; cb < 2; ++cb) {
            const int col = wcol0 + cb * 16 + lr;
            #pragma unroll
            for (int q = 0; q < 4; ++q) {
                const int e = rb * 16 + lk * 4 + q;
                const float hv = sspf(acc1[rb][cb][q] + (cb ? b1c1 : b1c0));
                const unsigned short hi = f2bf(hv);
                const int idx = e * NF + (col ^ ((e & 7) << 3));
                Ahi[idx] = hi;
                Alo[idx] = f2bf(hv - bf2f(hi));
            }
        }
    __syncthreads();

    f32x4 acc2[4][2] = {};
    #pragma unroll
    for (int rb = 0; rb < 4; ++rb) {
        short8 ah[4], al[4];
        #pragma unroll
        for (int kb = 0; kb < 4; ++kb) {
            const int e  = rb * 16 + lr;
            const int k0 = kb * 32 + lk * 8;
            const int idx = e * NF + (k0 ^ ((e & 7) << 3));
            ah[kb] = *reinterpret_cast<const short8*>(&Ahi[idx]);
            al[kb] = *reinterpret_cast<const short8*>(&Alo[idx]);
        }
        #pragma unroll
        for (int cb = 0; cb < 2; ++cb)
            #pragma unroll
            for (int kb = 0; kb < 4; ++kb) {
                acc2[rb][cb] = __builtin_amdgcn_mfma_f32_16x16x32_bf16(
                    ah[kb], w2fr[kb][cb], acc2[rb][cb], 0, 0, 0);
                acc2[rb][cb] = __builtin_amdgcn_mfma_f32_16x16x32_bf16(
                    al[kb], w2fr[kb][cb], acc2[rb][cb], 0, 0, 0);
            }
    }

    #pragma unroll
    for (int rb = 0; rb < 4; ++rb)
        #pragma unroll
        for (int cb = 0; cb < 2; ++cb) {
            const int col = wcol0 + cb * 16 + lr;
            #pragma unroll
            for (int q = 0; q < 4; ++q) {
                const int n = n0 + rb * 16 + lk * 4 + q;
                if (n < N)
                    out[(size_t)n * NF + col] = acc2[rb][cb][q] + (cb ? b2c1 : b2c0);
            }
        }
}

extern "C" void kernel_launch(void* const* d_in, const int* in_sizes, int n_in,
                              void* d_out, int out_size, void* d_ws, size_t ws_size,
                              hipStream_t stream)
{
    const float* x    = (const float*)d_in[0];
    const float* y    = (const float*)d_in[1];
    const float* f_ij = (const float*)d_in[2];
    const float* rcut = (const float*)d_in[3];
    const int* idx_i  = (const int*)d_in[4];
    const int* idx_j  = (const int*)d_in[5];
    const float* W_in2f   = (const float*)d_in[6];
    const float* W_in2f_y = (const float*)d_in[7];
    const float* Wf1 = (const float*)d_in[8];
    const float* bf1 = (const float*)d_in[9];
    const float* Wf2 = (const float*)d_in[10];
    const float* bf2 = (const float*)d_in[11];
    const float* Wx1 = (const float*)d_in[12];
    const float* bx1 = (const float*)d_in[13];
    const float* Wx2 = (const float*)d_in[14];
    const float* bx2 = (const float*)d_in[15];
    const float* Wy1 = (const float*)d_in[16];
    const float* by1 = (const float*)d_in[17];
    const float* Wy2 = (const float*)d_in[18];
    const float* by2 = (const float*)d_in[19];

    const int N = in_sizes[0] / NF;
    const int E = in_sizes[4];
    const size_t NNF = (size_t)N * NF;

    _Float16* xf = (_Float16*)d_out;
    _Float16* yf = xf + NNF;
    float* ox = (float*)d_out;
    float* oy = ox + NNF;

    // upper half of d_out: sort scratch + sorted edge data (dead before
    // out_fused writes). Budget: 1.6 + 2.4 + 7.2 + 38.4 = 49.6 MB <= 51.2 MB.
    char* ub = (char*)d_out + 4 * NNF;
    int* deg   = (int*)ub;
    int* loc   = deg + N;
    int* rowp  = loc + N;
    int* cur   = rowp + N;
    int* parts = cur + N;              // 64 ints
    int* ord   = parts + 64;           // E
    int* nis   = ord + E;              // E
    int* jos   = nis + E;              // E
    float* rcs = (float*)(jos + E);    // E
    _Float16* f16s = (_Float16*)(rcs + E);   // E * 32 halves

    float* conv_x = (float*)d_ws;
    float* conv_y = conv_x + NNF;

    const int NB = (N + 2047) / 2048;
    const int nodeTiles = (N + 63) / 64;
    const int nGroups = (N + 15) / 16;

    hipMemsetAsync(deg, 0, (size_t)N * sizeof(int), stream);

    proj_mfma_kernel<<<dim3(nodeTiles, 2), 256, 0, stream>>>(
        x, y, W_in2f, W_in2f_y, xf, yf, conv_y, N);

    hist1_kernel<<<1024, 256, 0, stream>>>(idx_i, deg, E);
    scanA1_kernel<<<NB, 256, 0, stream>>>(deg, loc, parts, N);
    scanB1_kernel<<<1, 64, 0, stream>>>(parts, NB);
    scanC1_kernel<<<128, 256, 0, stream>>>(loc, parts, rowp, cur, N);
    scatter1_kernel<<<1024, 256, 0, stream>>>(idx_i, idx_j, rcut, cur, ord,
                                              nis, jos, rcs, E);
    fsort_kernel<<<2048, 256, 0, stream>>>(f_ij, ord, f16s, E);

    edge_hybrid_kernel<<<nGroups, 256, 0, stream>>>(
        f16s, nis, jos, rcs, Wf1, bf1, Wf2, bf2, xf, yf,
        rowp, conv_x, conv_y, N, E);

    out_fused_kernel<<<dim3(nodeTiles, 2), 256, 0, stream>>>(
        conv_x, conv_y, Wx1, Wy1, bx1, by1, Wx2, Wy2, bx2, by2,
        ox, oy, N);
}

// Round 21
// 632.517 us; speedup vs baseline: 1.2053x; 1.0238x over previous
//
#include <hip/hip_runtime.h>
#include <hip/hip_bf16.h>

#define NF 128
#define RBF 20

using half8 = __attribute__((ext_vector_type(8))) _Float16;
using f32x4 = __attribute__((ext_vector_type(4))) float;

__device__ __forceinline__ float sspf(float v) {
    const float t = __expf(-fabsf(v));
    return fmaxf(v, 0.f) + __logf(1.f + t) - 0.69314718055994531f;
}

// ---------------------------------------------------------------------------
// Counting sort by idx_i; sorted meta AND f-rows materialized at scatter.
// ---------------------------------------------------------------------------
__global__ void hist1_kernel(const int* __restrict__ idx, int* __restrict__ deg, int E)
{
    for (int e = blockIdx.x * blockDim.x + threadIdx.x; e < E;
         e += gridDim.x * blockDim.x)
        atomicAdd(&deg[idx[e]], 1);
}

__global__ void scanA1_kernel(const int* __restrict__ deg, int* __restrict__ loc,
                              int* __restrict__ parts, int NN)
{
    const int tid = threadIdx.x;
    const int base = blockIdx.x * 2048;
    __shared__ int tsum[256];
    int v[8]; int s = 0;
    #pragma unroll
    for (int r = 0; r < 8; ++r) {
        const int idx = base + tid * 8 + r;
        v[r] = (idx < NN) ? deg[idx] : 0;
        s += v[r];
    }
    tsum[tid] = s;
    __syncthreads();
    #pragma unroll
    for (int d = 1; d < 256; d <<= 1) {
        const int add = (tid >= d) ? tsum[tid - d] : 0;
        __syncthreads();
        tsum[tid] += add;
        __syncthreads();
    }
    int run = tsum[tid] - s;
    #pragma unroll
    for (int r = 0; r < 8; ++r) {
        const int idx = base + tid * 8 + r;
        if (idx < NN) loc[idx] = run;
        run += v[r];
    }
    if (tid == 0) parts[blockIdx.x] = tsum[255];
}

__global__ void scanB1_kernel(int* __restrict__ parts, int NB)
{
    __shared__ int p[64];
    const int t = threadIdx.x;
    p[t] = (t < NB) ? parts[t] : 0;
    __syncthreads();
    #pragma unroll
    for (int d = 1; d < 64; d <<= 1) {
        const int add = (t >= d) ? p[t - d] : 0;
        __syncthreads();
        p[t] += add;
        __syncthreads();
    }
    parts[t] = (t > 0) ? p[t - 1] : 0;
}

__global__ void scanC1_kernel(const int* __restrict__ loc, const int* __restrict__ parts,
                              int* __restrict__ rowp, int* __restrict__ cur, int NN)
{
    for (int i = blockIdx.x * blockDim.x + threadIdx.x; i < NN;
         i += gridDim.x * blockDim.x) {
        const int v = loc[i] + parts[i >> 11];
        rowp[i] = v;
        cur[i]  = v;
    }
}

// scatter + f-row materialization fused (reads coalesced by e, writes by p)
__global__ void scatter1_kernel(const int* __restrict__ idx_i, const int* __restrict__ idx_j,
                                const float* __restrict__ rcut,
                                const float* __restrict__ f_ij,
                                int* __restrict__ cur,
                                int* __restrict__ nis, int* __restrict__ jos,
                                float* __restrict__ rcs,
                                _Float16* __restrict__ f16s, int E)
{
    for (int e = blockIdx.x * blockDim.x + threadIdx.x; e < E;
         e += gridDim.x * blockDim.x) {
        const int key = idx_i[e];
        const int p = atomicAdd(&cur[key], 1);
        nis[p] = key;
        jos[p] = idx_j[e] * NF;
        rcs[p] = rcut[e];

        const float* src = f_ij + (size_t)e * RBF;
        _Float16 tmp[32];
        #pragma unroll
        for (int k4 = 0; k4 < 5; ++k4) {
            const float4 v = *reinterpret_cast<const float4*>(src + k4 * 4);
            tmp[k4 * 4 + 0] = (_Float16)v.x;
            tmp[k4 * 4 + 1] = (_Float16)v.y;
            tmp[k4 * 4 + 2] = (_Float16)v.z;
            tmp[k4 * 4 + 3] = (_Float16)v.w;
        }
        #pragma unroll
        for (int k = RBF; k < 32; ++k) tmp[k] = (_Float16)0.f;
        uint4* dst = reinterpret_cast<uint4*>(f16s + (size_t)p * 32);
        const uint4* s4 = reinterpret_cast<const uint4*>(tmp);
        dst[0] = s4[0]; dst[1] = s4[1]; dst[2] = s4[2]; dst[3] = s4[3];
    }
}

// ---------------------------------------------------------------------------
// Hybrid edge kernel: 256 threads (4 waves), ONE 16-node group per block.
// f A-frags loaded DIRECTLY from global (coalesced) — no f LDS stage,
// 5 barriers/tile. selector-MFMA conv_x + halved fp32 atomics conv_y.
// ---------------------------------------------------------------------------
__global__ __launch_bounds__(256, 2)
void edge_hybrid_kernel(const _Float16* __restrict__ f16s,
                        const int* __restrict__ nis,
                        const int* __restrict__ jos,
                        const float* __restrict__ rcs,
                        const float* __restrict__ Wf1,
                        const float* __restrict__ bf1,
                        const float* __restrict__ Wf2,
                        const float* __restrict__ bf2v,
                        const _Float16* __restrict__ xf,
                        const _Float16* __restrict__ yf,
                        const int* __restrict__ rowp,
                        float* __restrict__ conv_x,
                        float* __restrict__ conv_y,
                        int NN, int E)
{
    const int tid = threadIdx.x;
    const int l = tid & 63, w = tid >> 6;      // 4 waves
    const int lr = l & 15, lk = l >> 4;
    const int wcol0 = w * 32;

    __shared__ _Float16 M_s[32 * 137];         // 8.7 KB
    __shared__ _Float16 Ash[32 * 136];         // 8.5 KB: h (XOR swz) then g
    __shared__ _Float16 xown[16 * 136];        // 4.3 KB
    __shared__ int ni_s[32];
    __shared__ int jo_s[32];
    __shared__ float rc_s[32];

    half8 b1fr[2];
    #pragma unroll
    for (int cb = 0; cb < 2; ++cb) {
        const int col = wcol0 + cb * 16 + lr;
        #pragma unroll
        for (int j = 0; j < 8; ++j) {
            const int k = lk * 8 + j;
            b1fr[cb][j] = (k < RBF) ? (_Float16)Wf1[k * NF + col] : (_Float16)0.f;
        }
    }
    half8 b2fr[4][2];
    #pragma unroll
    for (int kb = 0; kb < 4; ++kb)
        #pragma unroll
        for (int cb = 0; cb < 2; ++cb) {
            const int col = wcol0 + cb * 16 + lr;
            #pragma unroll
            for (int j = 0; j < 8; ++j)
                b2fr[kb][cb][j] = (_Float16)Wf2[(size_t)(kb * 32 + lk * 8 + j) * NF + col];
        }
    const float b1c[2] = { bf1[wcol0 + lr], bf1[wcol0 + 16 + lr] };
    const float b2c[2] = { bf2v[wcol0 + lr], bf2v[wcol0 + 16 + lr] };

    const int n0 = blockIdx.x * 16;
    const int eb = rowp[n0];
    const int ee = (n0 + 16 < NN) ? rowp[n0 + 16] : E;
    const int nt = (ee - eb + 31) >> 5;

    // stage own xf rows [n0, n0+16): 1024 uints, stride 136
    #pragma unroll
    for (int u = 0; u < 4; ++u) {
        const int tt = u * 256 + tid;
        const int row = tt >> 6, cp = tt & 63;
        unsigned v = 0;
        if (n0 + row < NN)
            v = reinterpret_cast<const unsigned*>(xf)[(size_t)(n0 + row) * 64 + cp];
        *reinterpret_cast<unsigned*>(&xown[row * 136 + cp * 2]) = v;
    }

    f32x4 accS[2] = {};

    for (int t = 0; t < nt; ++t) {
        const int p0 = eb + t * 32;
        const int cnt = ee - p0;
        __syncthreads();               // prev-tile readers of M_s/Ash/meta/xown done

        // meta: LINEAR loads from sorted arrays
        if (tid < 32) {
            const int p = p0 + tid;
            const bool val = p < ee;
            ni_s[tid] = val ? nis[p] : -1;
            jo_s[tid] = val ? jos[p] : 0;
            rc_s[tid] = val ? rcs[p] : 0.f;
        }

        // phase 1: h = ssp(f @ W1 + b1); A-frag DIRECT from global (coalesced)
        f32x4 acc1[2][2] = {};
        #pragma unroll
        for (int rb = 0; rb < 2; ++rb) {
            int p = p0 + rb * 16 + lr;
            if (p >= E) p = E - 1;               // clamp; rc=0 kills contribution
            const half8 a = *reinterpret_cast<const half8*>(
                &f16s[(size_t)p * 32 + lk * 8]);
            #pragma unroll
            for (int cb = 0; cb < 2; ++cb)
                acc1[rb][cb] = __builtin_amdgcn_mfma_f32_16x16x32_f16(
                    a, b1fr[cb], acc1[rb][cb], 0, 0, 0);
        }
        #pragma unroll
        for (int rb = 0; rb < 2; ++rb)
            #pragma unroll
            for (int cb = 0; cb < 2; ++cb) {
                const int col = wcol0 + cb * 16 + lr;
                #pragma unroll
                for (int q = 0; q < 4; ++q) {
                    const int e = rb * 16 + lk * 4 + q;
                    const float hv = sspf(acc1[rb][cb][q] + b1c[cb]);
                    Ash[e * 136 + (col ^ ((e & 7) << 3))] = (_Float16)hv;
                }
            }
        __syncthreads();               // h ready; meta visible

        // EARLY: issue g gather loads (hide under phase-2 MFMA)
        unsigned gr[8];
        #pragma unroll
        for (int u = 0; u < 8; ++u) {
            const int tt = u * 256 + tid;
            const int slot = tt >> 6, cp = tt & 63;
            gr[u] = reinterpret_cast<const unsigned*>(yf)[(jo_s[slot] >> 1) + cp];
        }

        // phase 2: wij = h @ W2
        f32x4 acc2[2][2] = {};
        #pragma unroll
        for (int rb = 0; rb < 2; ++rb) {
            half8 a[4];
            #pragma unroll
            for (int kb = 0; kb < 4; ++kb) {
                const int e  = rb * 16 + lr;
                const int k0 = kb * 32 + lk * 8;
                a[kb] = *reinterpret_cast<const half8*>(
                    &Ash[e * 136 + (k0 ^ ((e & 7) << 3))]);
            }
            #pragma unroll
            for (int cb = 0; cb < 2; ++cb)
                #pragma unroll
                for (int kb = 0; kb < 4; ++kb)
                    acc2[rb][cb] = __builtin_amdgcn_mfma_f32_16x16x32_f16(
                        a[kb], b2fr[kb][cb], acc2[rb][cb], 0, 0, 0);
        }
        __syncthreads();            // h reads done -> Ash reusable for g

        // g ds_writes into Ash (stride 136) from prefetched registers
        #pragma unroll
        for (int u = 0; u < 8; ++u) {
            const int tt = u * 256 + tid;
            const int slot = tt >> 6, cp = tt & 63;
            *reinterpret_cast<unsigned*>(&Ash[slot * 136 + cp * 2]) = gr[u];
        }
        __syncthreads();

        // per-thread: M = wv*g -> M_s + y-side atomics (valid slots only)
        #pragma unroll
        for (int rb = 0; rb < 2; ++rb)
            #pragma unroll
            for (int cb = 0; cb < 2; ++cb) {
                const int col = wcol0 + cb * 16 + lr;
                #pragma unroll
                for (int q = 0; q < 4; ++q) {
                    const int e = rb * 16 + lk * 4 + q;
                    const float wv = (acc2[rb][cb][q] + b2c[cb]) * rc_s[e];
                    const float g  = (float)Ash[e * 136 + col];
                    M_s[e * 137 + col] = (_Float16)(wv * g);
                    if (e < cnt) {
                        const int oi = ni_s[e] - n0;
                        const float xo = (float)xown[oi * 136 + col];
                        unsafeAtomicAdd(&conv_y[(size_t)jo_s[e] + col], xo * wv);
                    }
                }
            }
        __syncthreads();

        // phase 3: accS += S @ M  (selector one-hot, K=32)
        {
            half8 as;
            int nn[8];
            #pragma unroll
            for (int j = 0; j < 8; ++j) nn[j] = ni_s[lk * 8 + j];
            const int node = n0 + lr;
            #pragma unroll
            for (int j = 0; j < 8; ++j)
                as[j] = (nn[j] == node) ? (_Float16)1.f : (_Float16)0.f;
            #pragma unroll
            for (int cb = 0; cb < 2; ++cb) {
                const int col = wcol0 + cb * 16 + lr;
                half8 bm;
                #pragma unroll
                for (int j = 0; j < 8; ++j)
                    bm[j] = M_s[(lk * 8 + j) * 137 + col];
                accS[cb] = __builtin_amdgcn_mfma_f32_16x16x32_f16(
                    as, bm, accS[cb], 0, 0, 0);
            }
        }
    }

    // conv_x rows [n0, n0+16): written once, plain stores
    #pragma unroll
    for (int cb = 0; cb < 2; ++cb) {
        const int col = wcol0 + cb * 16 + lr;
        #pragma unroll
        for (int q = 0; q < 4; ++q) {
            const int n = n0 + lk * 4 + q;
            if (n < NN) conv_x[(size_t)n * NF + col] = accS[cb][q];
        }
    }
}

// ---------------------------------------------------------------------------
// Projection (exact grid, f16): out_f16 = in @ W (bias-free) + zero conv_y
// ---------------------------------------------------------------------------
__global__ __launch_bounds__(256, 2)
void proj_mfma_kernel(const float* in0, const float* in1,
                      const float* __restrict__ W0, const float* __restrict__ W1p,
                      _Float16* o0, _Float16* o1,
                      float* __restrict__ conv_y, int N)
{
    const float* in = blockIdx.y ? in1 : in0;
    const float* W  = blockIdx.y ? W1p : W0;
    _Float16* out   = blockIdx.y ? o1 : o0;

    const int tid = threadIdx.x;
    const int l = tid & 63, w = tid >> 6;
    const int lr = l & 15, lk = l >> 4;
    const int wcol0 = w * 32;

    __shared__ _Float16 Ahi[64 * NF];

    half8 bfr[4][2];
    #pragma unroll
    for (int kb = 0; kb < 4; ++kb)
        #pragma unroll
        for (int cb = 0; cb < 2; ++cb) {
            const int col = wcol0 + cb * 16 + lr;
            #pragma unroll
            for (int j = 0; j < 8; ++j)
                bfr[kb][cb][j] = (_Float16)W[(size_t)(kb * 32 + lk * 8 + j) * NF + col];
        }

    const int n0 = blockIdx.x * 64;
    #pragma unroll
    for (int s = 0; s < 32; ++s) {
        const int t = s * 256 + tid;
        const int row = t >> 7, cc = t & (NF - 1);
        const float v = (n0 + row < N) ? in[(size_t)(n0 + row) * NF + cc] : 0.f;
        Ahi[row * NF + (cc ^ ((row & 7) << 3))] = (_Float16)v;
    }
    {
        const float4 z = {0.f, 0.f, 0.f, 0.f};
        const int rbase = n0 + 32 * blockIdx.y;
        #pragma unroll
        for (int s = 0; s < 4; ++s) {
            const int t = s * 256 + tid;
            const int row = rbase + (t >> 5);
            if (row < N)
                *reinterpret_cast<float4*>(&conv_y[(size_t)row * NF + (t & 31) * 4]) = z;
        }
    }
    __syncthreads();

    f32x4 acc[4][2] = {};
    #pragma unroll
    for (int rb = 0; rb < 4; ++rb) {
        half8 a[4];
        #pragma unroll
        for (int kb = 0; kb < 4; ++kb) {
            const int e  = rb * 16 + lr;
            const int k0 = kb * 32 + lk * 8;
            a[kb] = *reinterpret_cast<const half8*>(&Ahi[e * NF + (k0 ^ ((e & 7) << 3))]);
        }
        #pragma unroll
        for (int cb = 0; cb < 2; ++cb)
            #pragma unroll
            for (int kb = 0; kb < 4; ++kb)
                acc[rb][cb] = __builtin_amdgcn_mfma_f32_16x16x32_f16(
                    a[kb], bfr[kb][cb], acc[rb][cb], 0, 0, 0);
    }

    #pragma unroll
    for (int rb = 0; rb < 4; ++rb)
        #pragma unroll
        for (int cb = 0; cb < 2; ++cb) {
            const int col = wcol0 + cb * 16 + lr;
            #pragma unroll
            for (int q = 0; q < 4; ++q) {
                const int n = n0 + rb * 16 + lk * 4 + q;
                if (n < N) out[(size_t)n * NF + col] = (_Float16)acc[rb][cb][q];
            }
        }
}

// ---------------------------------------------------------------------------
// Fused output MLP (exact grid, plain f16): out = ssp(conv@W1+b1)@W2 + b2
// ---------------------------------------------------------------------------
__global__ __launch_bounds__(256, 2)
void out_fused_kernel(const float* conv0, const float* conv1,
                      const float* __restrict__ W10, const float* __restrict__ W11,
                      const float* __restrict__ b10, const float* __restrict__ b11,
                      const float* __restrict__ W20, const float* __restrict__ W21,
                      const float* __restrict__ b20, const float* __restrict__ b21,
                      float* o0, float* o1, int N)
{
    const float* in = blockIdx.y ? conv1 : conv0;
    const float* W1 = blockIdx.y ? W11 : W10;
    const float* b1 = blockIdx.y ? b11 : b10;
    const float* W2 = blockIdx.y ? W21 : W20;
    const float* b2 = blockIdx.y ? b21 : b20;
    float* out      = blockIdx.y ? o1  : o0;

    const int tid = threadIdx.x;
    const int l = tid & 63, w = tid >> 6;
    const int lr = l & 15, lk = l >> 4;
    const int wcol0 = w * 32;

    __shared__ _Float16 Ahi[64 * NF];

    half8 w1fr[4][2], w2fr[4][2];
    #pragma unroll
    for (int kb = 0; kb < 4; ++kb)
        #pragma unroll
        for (int cb = 0; cb < 2; ++cb) {
            const int col = wcol0 + cb * 16 + lr;
            #pragma unroll
            for (int j = 0; j < 8; ++j) {
                const size_t kk = (size_t)(kb * 32 + lk * 8 + j) * NF + col;
                w1fr[kb][cb][j] = (_Float16)W1[kk];
                w2fr[kb][cb][j] = (_Float16)W2[kk];
            }
        }
    const float b1c0 = b1[wcol0 + lr], b1c1 = b1[wcol0 + 16 + lr];
    const float b2c0 = b2[wcol0 + lr], b2c1 = b2[wcol0 + 16 + lr];

    const int n0 = blockIdx.x * 64;
    #pragma unroll
    for (int s = 0; s < 32; ++s) {
        const int t = s * 256 + tid;
        const int row = t >> 7, cc = t & (NF - 1);
        const float v = (n0 + row < N) ? in[(size_t)(n0 + row) * NF + cc] : 0.f;
        Ahi[row * NF + (cc ^ ((row & 7) << 3))] = (_Float16)v;
    }
    __syncthreads();

    f32x4 acc1[4][2] = {};
    #pragma unroll
    for (int rb = 0; rb < 4; ++rb) {
        half8 a[4];
        #pragma unroll
        for (int kb = 0; kb < 4; ++kb) {
            const int e  = rb * 16 + lr;
            const int k0 = kb * 32 + lk * 8;
            a[kb] = *reinterpret_cast<const half8*>(&Ahi[e * NF + (k0 ^ ((e & 7) << 3))]);
        }
        #pragma unroll
        for (int cb = 0; cb < 2; ++cb)
            #pragma unroll
            for (int kb = 0; kb < 4; ++kb)
                acc1[rb][cb] = __builtin_amdgcn_mfma_f32_16x16x32_f16(
                    a[kb], w1fr[kb][cb], acc1[rb][cb], 0, 0, 0);
    }
    __syncthreads();

    #pragma unroll
    for (int rb = 0; rb < 4; ++rb)
        #pragma unroll
        for (int cb = 0; cb < 2; ++cb) {
            const int col = wcol0 + cb * 16 + lr;
            #pragma unroll
            for (int q = 0; q < 4; ++q) {
                const int e = rb * 16 + lk * 4 + q;
                const float hv = sspf(acc1[rb][cb][q] + (cb ? b1c1 : b1c0));
                Ahi[e * NF + (col ^ ((e & 7) << 3))] = (_Float16)hv;
            }
        }
    __syncthreads();

    f32x4 acc2[4][2] = {};
    #pragma unroll
    for (int rb = 0; rb < 4; ++rb) {
        half8 a[4];
        #pragma unroll
        for (int kb = 0; kb < 4; ++kb) {
            const int e  = rb * 16 + lr;
            const int k0 = kb * 32 + lk * 8;
            a[kb] = *reinterpret_cast<const half8*>(&Ahi[e * NF + (k0 ^ ((e & 7) << 3))]);
        }
        #pragma unroll
        for (int cb = 0; cb < 2; ++cb)
            #pragma unroll
            for (int kb = 0; kb < 4; ++kb)
                acc2[rb][cb] = __builtin_amdgcn_mfma_f32_16x16x32_f16(
                    a[kb], w2fr[kb][cb], acc2[rb][cb], 0, 0, 0);
    }

    #pragma unroll
    for (int rb = 0; rb < 4; ++rb)
        #pragma unroll
        for (int cb = 0; cb < 2; ++cb) {
            const int col = wcol0 + cb * 16 + lr;
            #pragma unroll
            for (int q = 0; q < 4; ++q) {
                const int n = n0 + rb * 16 + lk * 4 + q;
                if (n < N)
                    out[(size_t)n * NF + col] = acc2[rb][cb][q] + (cb ? b2c1 : b2c0);
            }
        }
}

extern "C" void kernel_launch(void* const* d_in, const int* in_sizes, int n_in,
                              void* d_out, int out_size, void* d_ws, size_t ws_size,
                              hipStream_t stream)
{
    const float* x    = (const float*)d_in[0];
    const float* y    = (const float*)d_in[1];
    const float* f_ij = (const float*)d_in[2];
    const float* rcut = (const float*)d_in[3];
    const int* idx_i  = (const int*)d_in[4];
    const int* idx_j  = (const int*)d_in[5];
    const float* W_in2f   = (const float*)d_in[6];
    const float* W_in2f_y = (const float*)d_in[7];
    const float* Wf1 = (const float*)d_in[8];
    const float* bf1 = (const float*)d_in[9];
    const float* Wf2 = (const float*)d_in[10];
    const float* bf2 = (const float*)d_in[11];
    const float* Wx1 = (const float*)d_in[12];
    const float* bx1 = (const float*)d_in[13];
    const float* Wx2 = (const float*)d_in[14];
    const float* bx2 = (const float*)d_in[15];
    const float* Wy1 = (const float*)d_in[16];
    const float* by1 = (const float*)d_in[17];
    const float* Wy2 = (const float*)d_in[18];
    const float* by2 = (const float*)d_in[19];

    const int N = in_sizes[0] / NF;
    const int E = in_sizes[4];
    const size_t NNF = (size_t)N * NF;

    _Float16* xf = (_Float16*)d_out;
    _Float16* yf = xf + NNF;
    float* ox = (float*)d_out;
    float* oy = ox + NNF;

    // upper half of d_out: sort scratch + sorted edge data (dead before
    // out_fused writes). Budget: 1.6 + 7.2 + 38.4 = 47.2 MB <= 51.2 MB.
    char* ub = (char*)d_out + 4 * NNF;
    int* deg   = (int*)ub;
    int* loc   = deg + N;
    int* rowp  = loc + N;
    int* cur   = rowp + N;
    int* parts = cur + N;              // 64 ints
    int* nis   = parts + 64;           // E
    int* jos   = nis + E;              // E
    float* rcs = (float*)(jos + E);    // E
    _Float16* f16s = (_Float16*)(rcs + E);   // E * 32 halves (64B-aligned)

    float* conv_x = (float*)d_ws;
    float* conv_y = conv_x + NNF;

    const int NB = (N + 2047) / 2048;
    const int nodeTiles = (N + 63) / 64;
    const int nGroups = (N + 15) / 16;

    hipMemsetAsync(deg, 0, (size_t)N * sizeof(int), stream);

    proj_mfma_kernel<<<dim3(nodeTiles, 2), 256, 0, stream>>>(
        x, y, W_in2f, W_in2f_y, xf, yf, conv_y, N);

    hist1_kernel<<<1024, 256, 0, stream>>>(idx_i, deg, E);
    scanA1_kernel<<<NB, 256, 0, stream>>>(deg, loc, parts, N);
    scanB1_kernel<<<1, 64, 0, stream>>>(parts, NB);
    scanC1_kernel<<<128, 256, 0, stream>>>(loc, parts, rowp, cur, N);
    scatter1_kernel<<<2048, 256, 0, stream>>>(idx_i, idx_j, rcut, f_ij, cur,
                                              nis, jos, rcs, f16s, E);

    edge_hybrid_kernel<<<nGroups, 256, 0, stream>>>(
        f16s, nis, jos, rcs, Wf1, bf1, Wf2, bf2, xf, yf,
        rowp, conv_x, conv_y, N, E);

    out_fused_kernel<<<dim3(nodeTiles, 2), 256, 0, stream>>>(
        conv_x, conv_y, Wx1, Wy1, bx1, by1, Wx2, Wy2, bx2, by2,
        ox, oy, N);
}

// Round 22
// 584.528 us; speedup vs baseline: 1.3043x; 1.0821x over previous
//
#include <hip/hip_runtime.h>
#include <hip/hip_bf16.h>

#define NF 128
#define RBF 20

using half8 = __attribute__((ext_vector_type(8))) _Float16;
using f32x4 = __attribute__((ext_vector_type(4))) float;

__device__ __forceinline__ float sspf(float v) {
    const float t = __expf(-fabsf(v));
    return fmaxf(v, 0.f) + __logf(1.f + t) - 0.69314718055994531f;
}

// ---------------------------------------------------------------------------
// Counting sort by idx_i; sorted meta AND f-rows materialized at scatter.
// ---------------------------------------------------------------------------
__global__ void scanA1_kernel(const int* __restrict__ deg, int* __restrict__ loc,
                              int* __restrict__ parts, int NN)
{
    const int tid = threadIdx.x;
    const int base = blockIdx.x * 2048;
    __shared__ int tsum[256];
    int v[8]; int s = 0;
    #pragma unroll
    for (int r = 0; r < 8; ++r) {
        const int idx = base + tid * 8 + r;
        v[r] = (idx < NN) ? deg[idx] : 0;
        s += v[r];
    }
    tsum[tid] = s;
    __syncthreads();
    #pragma unroll
    for (int d = 1; d < 256; d <<= 1) {
        const int add = (tid >= d) ? tsum[tid - d] : 0;
        __syncthreads();
        tsum[tid] += add;
        __syncthreads();
    }
    int run = tsum[tid] - s;
    #pragma unroll
    for (int r = 0; r < 8; ++r) {
        const int idx = base + tid * 8 + r;
        if (idx < NN) loc[idx] = run;
        run += v[r];
    }
    if (tid == 0) parts[blockIdx.x] = tsum[255];
}

__global__ void scanB1_kernel(int* __restrict__ parts, int NB)
{
    __shared__ int p[64];
    const int t = threadIdx.x;
    p[t] = (t < NB) ? parts[t] : 0;
    __syncthreads();
    #pragma unroll
    for (int d = 1; d < 64; d <<= 1) {
        const int add = (t >= d) ? p[t - d] : 0;
        __syncthreads();
        p[t] += add;
        __syncthreads();
    }
    parts[t] = (t > 0) ? p[t - 1] : 0;
}

__global__ void scanC1_kernel(const int* __restrict__ loc, const int* __restrict__ parts,
                              int* __restrict__ rowp, int* __restrict__ cur, int NN)
{
    for (int i = blockIdx.x * blockDim.x + threadIdx.x; i < NN;
         i += gridDim.x * blockDim.x) {
        const int v = loc[i] + parts[i >> 11];
        rowp[i] = v;
        cur[i]  = v;
    }
}

// scatter + f-row materialization fused (reads coalesced by e, writes by p)
__global__ void scatter1_kernel(const int* __restrict__ idx_i, const int* __restrict__ idx_j,
                                const float* __restrict__ rcut,
                                const float* __restrict__ f_ij,
                                int* __restrict__ cur,
                                int* __restrict__ nis, int* __restrict__ jos,
                                float* __restrict__ rcs,
                                _Float16* __restrict__ f16s, int E)
{
    for (int e = blockIdx.x * blockDim.x + threadIdx.x; e < E;
         e += gridDim.x * blockDim.x) {
        const int key = idx_i[e];
        const int p = atomicAdd(&cur[key], 1);
        nis[p] = key;
        jos[p] = idx_j[e] * NF;
        rcs[p] = rcut[e];

        const float* src = f_ij + (size_t)e * RBF;
        _Float16 tmp[32];
        #pragma unroll
        for (int k4 = 0; k4 < 5; ++k4) {
            const float4 v = *reinterpret_cast<const float4*>(src + k4 * 4);
            tmp[k4 * 4 + 0] = (_Float16)v.x;
            tmp[k4 * 4 + 1] = (_Float16)v.y;
            tmp[k4 * 4 + 2] = (_Float16)v.z;
            tmp[k4 * 4 + 3] = (_Float16)v.w;
        }
        #pragma unroll
        for (int k = RBF; k < 32; ++k) tmp[k] = (_Float16)0.f;
        uint4* dst = reinterpret_cast<uint4*>(f16s + (size_t)p * 32);
        const uint4* s4 = reinterpret_cast<const uint4*>(tmp);
        dst[0] = s4[0]; dst[1] = s4[1]; dst[2] = s4[2]; dst[3] = s4[3];
    }
}

// ---------------------------------------------------------------------------
// Hybrid edge kernel: 256 threads (4 waves), ONE 16-node group per block.
// 4 barriers/tile: f direct from global; g staged in M_s and consumed/
// overwritten in place. selector-MFMA conv_x + halved fp32 atomics conv_y.
// ---------------------------------------------------------------------------
__global__ __launch_bounds__(256, 2)
void edge_hybrid_kernel(const _Float16* __restrict__ f16s,
                        const int* __restrict__ nis,
                        const int* __restrict__ jos,
                        const float* __restrict__ rcs,
                        const float* __restrict__ Wf1,
                        const float* __restrict__ bf1,
                        const float* __restrict__ Wf2,
                        const float* __restrict__ bf2v,
                        const _Float16* __restrict__ xf,
                        const _Float16* __restrict__ yf,
                        const int* __restrict__ rowp,
                        float* __restrict__ conv_x,
                        float* __restrict__ conv_y,
                        int NN, int E)
{
    const int tid = threadIdx.x;
    const int l = tid & 63, w = tid >> 6;      // 4 waves
    const int lr = l & 15, lk = l >> 4;
    const int wcol0 = w * 32;

    __shared__ _Float16 M_s[32 * 138];         // 8.8 KB: g then M (in place)
    __shared__ _Float16 Ash[32 * 136];         // 8.5 KB: h (XOR swz)
    __shared__ _Float16 xown[16 * 136];        // 4.3 KB
    __shared__ int ni_s[32];
    __shared__ int jo_s[32];
    __shared__ float rc_s[32];

    half8 b1fr[2];
    #pragma unroll
    for (int cb = 0; cb < 2; ++cb) {
        const int col = wcol0 + cb * 16 + lr;
        #pragma unroll
        for (int j = 0; j < 8; ++j) {
            const int k = lk * 8 + j;
            b1fr[cb][j] = (k < RBF) ? (_Float16)Wf1[k * NF + col] : (_Float16)0.f;
        }
    }
    half8 b2fr[4][2];
    #pragma unroll
    for (int kb = 0; kb < 4; ++kb)
        #pragma unroll
        for (int cb = 0; cb < 2; ++cb) {
            const int col = wcol0 + cb * 16 + lr;
            #pragma unroll
            for (int j = 0; j < 8; ++j)
                b2fr[kb][cb][j] = (_Float16)Wf2[(size_t)(kb * 32 + lk * 8 + j) * NF + col];
        }
    const float b1c[2] = { bf1[wcol0 + lr], bf1[wcol0 + 16 + lr] };
    const float b2c[2] = { bf2v[wcol0 + lr], bf2v[wcol0 + 16 + lr] };

    const int n0 = blockIdx.x * 16;
    const int eb = rowp[n0];
    const int ee = (n0 + 16 < NN) ? rowp[n0 + 16] : E;
    const int nt = (ee - eb + 31) >> 5;

    // stage own xf rows [n0, n0+16): 1024 uints, stride 136
    #pragma unroll
    for (int u = 0; u < 4; ++u) {
        const int tt = u * 256 + tid;
        const int row = tt >> 6, cp = tt & 63;
        unsigned v = 0;
        if (n0 + row < NN)
            v = reinterpret_cast<const unsigned*>(xf)[(size_t)(n0 + row) * 64 + cp];
        *reinterpret_cast<unsigned*>(&xown[row * 136 + cp * 2]) = v;
    }

    f32x4 accS[2] = {};

    for (int t = 0; t < nt; ++t) {
        const int p0 = eb + t * 32;
        const int cnt = ee - p0;
        __syncthreads();               // prev-tile readers of M_s/Ash/meta done

        // meta: LINEAR loads from sorted arrays
        if (tid < 32) {
            const int p = p0 + tid;
            const bool val = p < ee;
            ni_s[tid] = val ? nis[p] : -1;
            jo_s[tid] = val ? jos[p] : 0;
            rc_s[tid] = val ? rcs[p] : 0.f;
        }

        // phase 1: h = ssp(f @ W1 + b1); A-frag DIRECT from global (coalesced)
        f32x4 acc1[2][2] = {};
        #pragma unroll
        for (int rb = 0; rb < 2; ++rb) {
            int p = p0 + rb * 16 + lr;
            if (p >= E) p = E - 1;               // clamp; rc=0 kills contribution
            const half8 a = *reinterpret_cast<const half8*>(
                &f16s[(size_t)p * 32 + lk * 8]);
            #pragma unroll
            for (int cb = 0; cb < 2; ++cb)
                acc1[rb][cb] = __builtin_amdgcn_mfma_f32_16x16x32_f16(
                    a, b1fr[cb], acc1[rb][cb], 0, 0, 0);
        }
        #pragma unroll
        for (int rb = 0; rb < 2; ++rb)
            #pragma unroll
            for (int cb = 0; cb < 2; ++cb) {
                const int col = wcol0 + cb * 16 + lr;
                #pragma unroll
                for (int q = 0; q < 4; ++q) {
                    const int e = rb * 16 + lk * 4 + q;
                    const float hv = sspf(acc1[rb][cb][q] + b1c[cb]);
                    Ash[e * 136 + (col ^ ((e & 7) << 3))] = (_Float16)hv;
                }
            }
        __syncthreads();               // h ready; meta visible

        // EARLY: issue g gather loads (hide under phase-2 MFMA)
        unsigned gr[8];
        #pragma unroll
        for (int u = 0; u < 8; ++u) {
            const int tt = u * 256 + tid;
            const int slot = tt >> 6, cp = tt & 63;
            gr[u] = reinterpret_cast<const unsigned*>(yf)[(jo_s[slot] >> 1) + cp];
        }

        // phase 2: wij = h @ W2
        f32x4 acc2[2][2] = {};
        #pragma unroll
        for (int rb = 0; rb < 2; ++rb) {
            half8 a[4];
            #pragma unroll
            for (int kb = 0; kb < 4; ++kb) {
                const int e  = rb * 16 + lr;
                const int k0 = kb * 32 + lk * 8;
                a[kb] = *reinterpret_cast<const half8*>(
                    &Ash[e * 136 + (k0 ^ ((e & 7) << 3))]);
            }
            #pragma unroll
            for (int cb = 0; cb < 2; ++cb)
                #pragma unroll
                for (int kb = 0; kb < 4; ++kb)
                    acc2[rb][cb] = __builtin_amdgcn_mfma_f32_16x16x32_f16(
                        a[kb], b2fr[kb][cb], acc2[rb][cb], 0, 0, 0);
        }

        // g ds_writes into M_s (stride 138, free since top sync)
        #pragma unroll
        for (int u = 0; u < 8; ++u) {
            const int tt = u * 256 + tid;
            const int slot = tt >> 6, cp = tt & 63;
            *reinterpret_cast<unsigned*>(&M_s[slot * 138 + cp * 2]) = gr[u];
        }
        __syncthreads();               // g visible; phase-2 Ash reads done

        // per-thread: M = wv*g in place + y-side atomics (valid slots only)
        #pragma unroll
        for (int rb = 0; rb < 2; ++rb)
            #pragma unroll
            for (int cb = 0; cb < 2; ++cb) {
                const int col = wcol0 + cb * 16 + lr;
                #pragma unroll
                for (int q = 0; q < 4; ++q) {
                    const int e = rb * 16 + lk * 4 + q;
                    const float wv = (acc2[rb][cb][q] + b2c[cb]) * rc_s[e];
                    const float g  = (float)M_s[e * 138 + col];
                    M_s[e * 138 + col] = (_Float16)(wv * g);
                    if (e < cnt) {
                        const int oi = ni_s[e] - n0;
                        const float xo = (float)xown[oi * 136 + col];
                        unsafeAtomicAdd(&conv_y[(size_t)jo_s[e] + col], xo * wv);
                    }
                }
            }
        __syncthreads();

        // phase 3: accS += S @ M  (selector one-hot, K=32)
        {
            half8 as;
            int nn[8];
            #pragma unroll
            for (int j = 0; j < 8; ++j) nn[j] = ni_s[lk * 8 + j];
            const int node = n0 + lr;
            #pragma unroll
            for (int j = 0; j < 8; ++j)
                as[j] = (nn[j] == node) ? (_Float16)1.f : (_Float16)0.f;
            #pragma unroll
            for (int cb = 0; cb < 2; ++cb) {
                const int col = wcol0 + cb * 16 + lr;
                half8 bm;
                #pragma unroll
                for (int j = 0; j < 8; ++j)
                    bm[j] = M_s[(lk * 8 + j) * 138 + col];
                accS[cb] = __builtin_amdgcn_mfma_f32_16x16x32_f16(
                    as, bm, accS[cb], 0, 0, 0);
            }
        }
    }

    // conv_x rows [n0, n0+16): written once, plain stores
    #pragma unroll
    for (int cb = 0; cb < 2; ++cb) {
        const int col = wcol0 + cb * 16 + lr;
        #pragma unroll
        for (int q = 0; q < 4; ++q) {
            const int n = n0 + lk * 4 + q;
            if (n < NN) conv_x[(size_t)n * NF + col] = accS[cb][q];
        }
    }
}

// ---------------------------------------------------------------------------
// Projection (exact grid, f16) + fused edge histogram + conv_y zero.
// ---------------------------------------------------------------------------
__global__ __launch_bounds__(256, 2)
void proj_mfma_kernel(const float* in0, const float* in1,
                      const float* __restrict__ W0, const float* __restrict__ W1p,
                      _Float16* o0, _Float16* o1,
                      float* __restrict__ conv_y,
                      const int* __restrict__ idx_i, int* __restrict__ deg,
                      int N, int E)
{
    const float* in = blockIdx.y ? in1 : in0;
    const float* W  = blockIdx.y ? W1p : W0;
    _Float16* out   = blockIdx.y ? o1 : o0;

    const int tid = threadIdx.x;
    const int l = tid & 63, w = tid >> 6;
    const int lr = l & 15, lk = l >> 4;
    const int wcol0 = w * 32;

    __shared__ _Float16 Ahi[64 * NF];

    // fused histogram slice (deg pre-zeroed by memset on same stream)
    {
        const int nb = gridDim.x * 2;
        const int bid = blockIdx.y * gridDim.x + blockIdx.x;
        for (int e = bid * 256 + tid; e < E; e += nb * 256)
            atomicAdd(&deg[idx_i[e]], 1);
    }

    half8 bfr[4][2];
    #pragma unroll
    for (int kb = 0; kb < 4; ++kb)
        #pragma unroll
        for (int cb = 0; cb < 2; ++cb) {
            const int col = wcol0 + cb * 16 + lr;
            #pragma unroll
            for (int j = 0; j < 8; ++j)
                bfr[kb][cb][j] = (_Float16)W[(size_t)(kb * 32 + lk * 8 + j) * NF + col];
        }

    const int n0 = blockIdx.x * 64;
    #pragma unroll
    for (int s = 0; s < 32; ++s) {
        const int t = s * 256 + tid;
        const int row = t >> 7, cc = t & (NF - 1);
        const float v = (n0 + row < N) ? in[(size_t)(n0 + row) * NF + cc] : 0.f;
        Ahi[row * NF + (cc ^ ((row & 7) << 3))] = (_Float16)v;
    }
    {
        const float4 z = {0.f, 0.f, 0.f, 0.f};
        const int rbase = n0 + 32 * blockIdx.y;
        #pragma unroll
        for (int s = 0; s < 4; ++s) {
            const int t = s * 256 + tid;
            const int row = rbase + (t >> 5);
            if (row < N)
                *reinterpret_cast<float4*>(&conv_y[(size_t)row * NF + (t & 31) * 4]) = z;
        }
    }
    __syncthreads();

    f32x4 acc[4][2] = {};
    #pragma unroll
    for (int rb = 0; rb < 4; ++rb) {
        half8 a[4];
        #pragma unroll
        for (int kb = 0; kb < 4; ++kb) {
            const int e  = rb * 16 + lr;
            const int k0 = kb * 32 + lk * 8;
            a[kb] = *reinterpret_cast<const half8*>(&Ahi[e * NF + (k0 ^ ((e & 7) << 3))]);
        }
        #pragma unroll
        for (int cb = 0; cb < 2; ++cb)
            #pragma unroll
            for (int kb = 0; kb < 4; ++kb)
                acc[rb][cb] = __builtin_amdgcn_mfma_f32_16x16x32_f16(
                    a[kb], bfr[kb][cb], acc[rb][cb], 0, 0, 0);
    }

    #pragma unroll
    for (int rb = 0; rb < 4; ++rb)
        #pragma unroll
        for (int cb = 0; cb < 2; ++cb) {
            const int col = wcol0 + cb * 16 + lr;
            #pragma unroll
            for (int q = 0; q < 4; ++q) {
                const int n = n0 + rb * 16 + lk * 4 + q;
                if (n < N) out[(size_t)n * NF + col] = (_Float16)acc[rb][cb][q];
            }
        }
}

// ---------------------------------------------------------------------------
// Fused output MLP (exact grid, plain f16): out = ssp(conv@W1+b1)@W2 + b2
// ---------------------------------------------------------------------------
__global__ __launch_bounds__(256, 2)
void out_fused_kernel(const float* conv0, const float* conv1,
                      const float* __restrict__ W10, const float* __restrict__ W11,
                      const float* __restrict__ b10, const float* __restrict__ b11,
                      const float* __restrict__ W20, const float* __restrict__ W21,
                      const float* __restrict__ b20, const float* __restrict__ b21,
                      float* o0, float* o1, int N)
{
    const float* in = blockIdx.y ? conv1 : conv0;
    const float* W1 = blockIdx.y ? W11 : W10;
    const float* b1 = blockIdx.y ? b11 : b10;
    const float* W2 = blockIdx.y ? W21 : W20;
    const float* b2 = blockIdx.y ? b21 : b20;
    float* out      = blockIdx.y ? o1  : o0;

    const int tid = threadIdx.x;
    const int l = tid & 63, w = tid >> 6;
    const int lr = l & 15, lk = l >> 4;
    const int wcol0 = w * 32;

    __shared__ _Float16 Ahi[64 * NF];

    half8 w1fr[4][2], w2fr[4][2];
    #pragma unroll
    for (int kb = 0; kb < 4; ++kb)
        #pragma unroll
        for (int cb = 0; cb < 2; ++cb) {
            const int col = wcol0 + cb * 16 + lr;
            #pragma unroll
            for (int j = 0; j < 8; ++j) {
                const size_t kk = (size_t)(kb * 32 + lk * 8 + j) * NF + col;
                w1fr[kb][cb][j] = (_Float16)W1[kk];
                w2fr[kb][cb][j] = (_Float16)W2[kk];
            }
        }
    const float b1c0 = b1[wcol0 + lr], b1c1 = b1[wcol0 + 16 + lr];
    const float b2c0 = b2[wcol0 + lr], b2c1 = b2[wcol0 + 16 + lr];

    const int n0 = blockIdx.x * 64;
    #pragma unroll
    for (int s = 0; s < 32; ++s) {
        const int t = s * 256 + tid;
        const int row = t >> 7, cc = t & (NF - 1);
        const float v = (n0 + row < N) ? in[(size_t)(n0 + row) * NF + cc] : 0.f;
        Ahi[row * NF + (cc ^ ((row & 7) << 3))] = (_Float16)v;
    }
    __syncthreads();

    f32x4 acc1[4][2] = {};
    #pragma unroll
    for (int rb = 0; rb < 4; ++rb) {
        half8 a[4];
        #pragma unroll
        for (int kb = 0; kb < 4; ++kb) {
            const int e  = rb * 16 + lr;
            const int k0 = kb * 32 + lk * 8;
            a[kb] = *reinterpret_cast<const half8*>(&Ahi[e * NF + (k0 ^ ((e & 7) << 3))]);
        }
        #pragma unroll
        for (int cb = 0; cb < 2; ++cb)
            #pragma unroll
            for (int kb = 0; kb < 4; ++kb)
                acc1[rb][cb] = __builtin_amdgcn_mfma_f32_16x16x32_f16(
                    a[kb], w1fr[kb][cb], acc1[rb][cb], 0, 0, 0);
    }
    __syncthreads();

    #pragma unroll
    for (int rb = 0; rb < 4; ++rb)
        #pragma unroll
        for (int cb = 0; cb < 2; ++cb) {
            const int col = wcol0 + cb * 16 + lr;
            #pragma unroll
            for (int q = 0; q < 4; ++q) {
                const int e = rb * 16 + lk * 4 + q;
                const float hv = sspf(acc1[rb][cb][q] + (cb ? b1c1 : b1c0));
                Ahi[e * NF + (col ^ ((e & 7) << 3))] = (_Float16)hv;
            }
        }
    __syncthreads();

    f32x4 acc2[4][2] = {};
    #pragma unroll
    for (int rb = 0; rb < 4; ++rb) {
        half8 a[4];
        #pragma unroll
        for (int kb = 0; kb < 4; ++kb) {
            const int e  = rb * 16 + lr;
            const int k0 = kb * 32 + lk * 8;
            a[kb] = *reinterpret_cast<const half8*>(&Ahi[e * NF + (k0 ^ ((e & 7) << 3))]);
        }
        #pragma unroll
        for (int cb = 0; cb < 2; ++cb)
            #pragma unroll
            for (int kb = 0; kb < 4; ++kb)
                acc2[rb][cb] = __builtin_amdgcn_mfma_f32_16x16x32_f16(
                    a[kb], w2fr[kb][cb], acc2[rb][cb], 0, 0, 0);
    }

    #pragma unroll
    for (int rb = 0; rb < 4; ++rb)
        #pragma unroll
        for (int cb = 0; cb < 2; ++cb) {
            const int col = wcol0 + cb * 16 + lr;
            #pragma unroll
            for (int q = 0; q < 4; ++q) {
                const int n = n0 + rb * 16 + lk * 4 + q;
                if (n < N)
                    out[(size_t)n * NF + col] = acc2[rb][cb][q] + (cb ? b2c1 : b2c0);
            }
        }
}

extern "C" void kernel_launch(void* const* d_in, const int* in_sizes, int n_in,
                              void* d_out, int out_size, void* d_ws, size_t ws_size,
                              hipStream_t stream)
{
    const float* x    = (const float*)d_in[0];
    const float* y    = (const float*)d_in[1];
    const float* f_ij = (const float*)d_in[2];
    const float* rcut = (const float*)d_in[3];
    const int* idx_i  = (const int*)d_in[4];
    const int* idx_j  = (const int*)d_in[5];
    const float* W_in2f   = (const float*)d_in[6];
    const float* W_in2f_y = (const float*)d_in[7];
    const float* Wf1 = (const float*)d_in[8];
    const float* bf1 = (const float*)d_in[9];
    const float* Wf2 = (const float*)d_in[10];
    const float* bf2 = (const float*)d_in[11];
    const float* Wx1 = (const float*)d_in[12];
    const float* bx1 = (const float*)d_in[13];
    const float* Wx2 = (const float*)d_in[14];
    const float* bx2 = (const float*)d_in[15];
    const float* Wy1 = (const float*)d_in[16];
    const float* by1 = (const float*)d_in[17];
    const float* Wy2 = (const float*)d_in[18];
    const float* by2 = (const float*)d_in[19];

    const int N = in_sizes[0] / NF;
    const int E = in_sizes[4];
    const size_t NNF = (size_t)N * NF;

    _Float16* xf = (_Float16*)d_out;
    _Float16* yf = xf + NNF;
    float* ox = (float*)d_out;
    float* oy = ox + NNF;

    // upper half of d_out: sort scratch + sorted edge data (dead before
    // out_fused writes). Budget: 1.6 + 7.2 + 38.4 = 47.2 MB <= 51.2 MB.
    char* ub = (char*)d_out + 4 * NNF;
    int* deg   = (int*)ub;
    int* loc   = deg + N;
    int* rowp  = loc + N;
    int* cur   = rowp + N;
    int* parts = cur + N;              // 64 ints
    int* nis   = parts + 64;           // E
    int* jos   = nis + E;              // E
    float* rcs = (float*)(jos + E);    // E
    _Float16* f16s = (_Float16*)(rcs + E);   // E * 32 halves (64B-aligned)

    float* conv_x = (float*)d_ws;
    float* conv_y = conv_x + NNF;

    const int NB = (N + 2047) / 2048;
    const int nodeTiles = (N + 63) / 64;
    const int nGroups = (N + 15) / 16;

    hipMemsetAsync(deg, 0, (size_t)N * sizeof(int), stream);

    proj_mfma_kernel<<<dim3(nodeTiles, 2), 256, 0, stream>>>(
        x, y, W_in2f, W_in2f_y, xf, yf, conv_y, idx_i, deg, N, E);

    scanA1_kernel<<<NB, 256, 0, stream>>>(deg, loc, parts, N);
    scanB1_kernel<<<1, 64, 0, stream>>>(parts, NB);
    scanC1_kernel<<<128, 256, 0, stream>>>(loc, parts, rowp, cur, N);
    scatter1_kernel<<<2048, 256, 0, stream>>>(idx_i, idx_j, rcut, f_ij, cur,
                                              nis, jos, rcs, f16s, E);

    edge_hybrid_kernel<<<nGroups, 256, 0, stream>>>(
        f16s, nis, jos, rcs, Wf1, bf1, Wf2, bf2, xf, yf,
        rowp, conv_x, conv_y, N, E);

    out_fused_kernel<<<dim3(nodeTiles, 2), 256, 0, stream>>>(
        conv_x, conv_y, Wx1, Wy1, bx1, by1, Wx2, Wy2, bx2, by2,
        ox, oy, N);
}

// Round 23
// 565.119 us; speedup vs baseline: 1.3491x; 1.0343x over previous
//
#include <hip/hip_runtime.h>
#include <hip/hip_bf16.h>

#define NF 128
#define RBF 20

using half8 = __attribute__((ext_vector_type(8))) _Float16;
using f32x4 = __attribute__((ext_vector_type(4))) float;

__device__ __forceinline__ float sspf(float v) {
    const float t = __expf(-fabsf(v));
    return fmaxf(v, 0.f) + __logf(1.f + t) - 0.69314718055994531f;
}

// ---------------------------------------------------------------------------
// Counting sort by idx_i; sorted meta AND f-rows materialized at scatter.
// ---------------------------------------------------------------------------
__global__ void scanA1_kernel(const int* __restrict__ deg, int* __restrict__ loc,
                              int* __restrict__ parts, int NN)
{
    const int tid = threadIdx.x;
    const int base = blockIdx.x * 2048;
    __shared__ int tsum[256];
    int v[8]; int s = 0;
    #pragma unroll
    for (int r = 0; r < 8; ++r) {
        const int idx = base + tid * 8 + r;
        v[r] = (idx < NN) ? deg[idx] : 0;
        s += v[r];
    }
    tsum[tid] = s;
    __syncthreads();
    #pragma unroll
    for (int d = 1; d < 256; d <<= 1) {
        const int add = (tid >= d) ? tsum[tid - d] : 0;
        __syncthreads();
        tsum[tid] += add;
        __syncthreads();
    }
    int run = tsum[tid] - s;
    #pragma unroll
    for (int r = 0; r < 8; ++r) {
        const int idx = base + tid * 8 + r;
        if (idx < NN) loc[idx] = run;
        run += v[r];
    }
    if (tid == 0) parts[blockIdx.x] = tsum[255];
}

__global__ void scanB1_kernel(int* __restrict__ parts, int NB)
{
    __shared__ int p[64];
    const int t = threadIdx.x;
    p[t] = (t < NB) ? parts[t] : 0;
    __syncthreads();
    #pragma unroll
    for (int d = 1; d < 64; d <<= 1) {
        const int add = (t >= d) ? p[t - d] : 0;
        __syncthreads();
        p[t] += add;
        __syncthreads();
    }
    parts[t] = (t > 0) ? p[t - 1] : 0;
}

__global__ void scanC1_kernel(const int* __restrict__ loc, const int* __restrict__ parts,
                              int* __restrict__ rowp, int* __restrict__ cur, int NN)
{
    for (int i = blockIdx.x * blockDim.x + threadIdx.x; i < NN;
         i += gridDim.x * blockDim.x) {
        const int v = loc[i] + parts[i >> 11];
        rowp[i] = v;
        cur[i]  = v;
    }
}

// scatter + f-row materialization fused (reads coalesced by e, writes by p)
__global__ void scatter1_kernel(const int* __restrict__ idx_i, const int* __restrict__ idx_j,
                                const float* __restrict__ rcut,
                                const float* __restrict__ f_ij,
                                int* __restrict__ cur,
                                int* __restrict__ nis, int* __restrict__ jos,
                                float* __restrict__ rcs,
                                _Float16* __restrict__ f16s, int E)
{
    for (int e = blockIdx.x * blockDim.x + threadIdx.x; e < E;
         e += gridDim.x * blockDim.x) {
        const int key = idx_i[e];
        const int p = atomicAdd(&cur[key], 1);
        nis[p] = key;
        jos[p] = idx_j[e] * NF;
        rcs[p] = rcut[e];

        const float* src = f_ij + (size_t)e * RBF;
        _Float16 tmp[32];
        #pragma unroll
        for (int k4 = 0; k4 < 5; ++k4) {
            const float4 v = *reinterpret_cast<const float4*>(src + k4 * 4);
            tmp[k4 * 4 + 0] = (_Float16)v.x;
            tmp[k4 * 4 + 1] = (_Float16)v.y;
            tmp[k4 * 4 + 2] = (_Float16)v.z;
            tmp[k4 * 4 + 3] = (_Float16)v.w;
        }
        #pragma unroll
        for (int k = RBF; k < 32; ++k) tmp[k] = (_Float16)0.f;
        uint4* dst = reinterpret_cast<uint4*>(f16s + (size_t)p * 32);
        const uint4* s4 = reinterpret_cast<const uint4*>(tmp);
        dst[0] = s4[0]; dst[1] = s4[1]; dst[2] = s4[2]; dst[3] = s4[3];
    }
}

// ---------------------------------------------------------------------------
// Hybrid edge kernel: 256 threads (4 waves), ONE 16-node group per block.
// 4 barriers/tile: f direct from global; g staged in M_s in place.
// selector-MFMA conv_x (f16 plain stores) + halved fp32 atomics conv_y.
// ---------------------------------------------------------------------------
__global__ __launch_bounds__(256, 2)
void edge_hybrid_kernel(const _Float16* __restrict__ f16s,
                        const int* __restrict__ nis,
                        const int* __restrict__ jos,
                        const float* __restrict__ rcs,
                        const float* __restrict__ Wf1,
                        const float* __restrict__ bf1,
                        const float* __restrict__ Wf2,
                        const float* __restrict__ bf2v,
                        const _Float16* __restrict__ xf,
                        const _Float16* __restrict__ yf,
                        const int* __restrict__ rowp,
                        _Float16* __restrict__ conv_x,
                        float* __restrict__ conv_y,
                        int NN, int E)
{
    const int tid = threadIdx.x;
    const int l = tid & 63, w = tid >> 6;      // 4 waves
    const int lr = l & 15, lk = l >> 4;
    const int wcol0 = w * 32;

    __shared__ _Float16 M_s[32 * 138];         // 8.8 KB: g then M (in place)
    __shared__ _Float16 Ash[32 * 136];         // 8.5 KB: h (XOR swz)
    __shared__ _Float16 xown[16 * 136];        // 4.3 KB
    __shared__ int ni_s[32];
    __shared__ int jo_s[32];
    __shared__ float rc_s[32];

    half8 b1fr[2];
    #pragma unroll
    for (int cb = 0; cb < 2; ++cb) {
        const int col = wcol0 + cb * 16 + lr;
        #pragma unroll
        for (int j = 0; j < 8; ++j) {
            const int k = lk * 8 + j;
            b1fr[cb][j] = (k < RBF) ? (_Float16)Wf1[k * NF + col] : (_Float16)0.f;
        }
    }
    half8 b2fr[4][2];
    #pragma unroll
    for (int kb = 0; kb < 4; ++kb)
        #pragma unroll
        for (int cb = 0; cb < 2; ++cb) {
            const int col = wcol0 + cb * 16 + lr;
            #pragma unroll
            for (int j = 0; j < 8; ++j)
                b2fr[kb][cb][j] = (_Float16)Wf2[(size_t)(kb * 32 + lk * 8 + j) * NF + col];
        }
    const float b1c[2] = { bf1[wcol0 + lr], bf1[wcol0 + 16 + lr] };
    const float b2c[2] = { bf2v[wcol0 + lr], bf2v[wcol0 + 16 + lr] };

    const int n0 = blockIdx.x * 16;
    const int eb = rowp[n0];
    const int ee = (n0 + 16 < NN) ? rowp[n0 + 16] : E;
    const int nt = (ee - eb + 31) >> 5;

    // stage own xf rows [n0, n0+16): 1024 uints, stride 136
    #pragma unroll
    for (int u = 0; u < 4; ++u) {
        const int tt = u * 256 + tid;
        const int row = tt >> 6, cp = tt & 63;
        unsigned v = 0;
        if (n0 + row < NN)
            v = reinterpret_cast<const unsigned*>(xf)[(size_t)(n0 + row) * 64 + cp];
        *reinterpret_cast<unsigned*>(&xown[row * 136 + cp * 2]) = v;
    }

    f32x4 accS[2] = {};

    for (int t = 0; t < nt; ++t) {
        const int p0 = eb + t * 32;
        const int cnt = ee - p0;
        __syncthreads();               // prev-tile readers of M_s/Ash/meta done

        // meta: LINEAR loads from sorted arrays
        if (tid < 32) {
            const int p = p0 + tid;
            const bool val = p < ee;
            ni_s[tid] = val ? nis[p] : -1;
            jo_s[tid] = val ? jos[p] : 0;
            rc_s[tid] = val ? rcs[p] : 0.f;
        }

        // phase 1: h = ssp(f @ W1 + b1); A-frag DIRECT from global (coalesced)
        f32x4 acc1[2][2] = {};
        #pragma unroll
        for (int rb = 0; rb < 2; ++rb) {
            int p = p0 + rb * 16 + lr;
            if (p >= E) p = E - 1;               // clamp; rc=0 kills contribution
            const half8 a = *reinterpret_cast<const half8*>(
                &f16s[(size_t)p * 32 + lk * 8]);
            #pragma unroll
            for (int cb = 0; cb < 2; ++cb)
                acc1[rb][cb] = __builtin_amdgcn_mfma_f32_16x16x32_f16(
                    a, b1fr[cb], acc1[rb][cb], 0, 0, 0);
        }
        #pragma unroll
        for (int rb = 0; rb < 2; ++rb)
            #pragma unroll
            for (int cb = 0; cb < 2; ++cb) {
                const int col = wcol0 + cb * 16 + lr;
                #pragma unroll
                for (int q = 0; q < 4; ++q) {
                    const int e = rb * 16 + lk * 4 + q;
                    const float hv = sspf(acc1[rb][cb][q] + b1c[cb]);
                    Ash[e * 136 + (col ^ ((e & 7) << 3))] = (_Float16)hv;
                }
            }
        __syncthreads();               // h ready; meta visible

        // EARLY: issue g gather loads (hide under phase-2 MFMA)
        unsigned gr[8];
        #pragma unroll
        for (int u = 0; u < 8; ++u) {
            const int tt = u * 256 + tid;
            const int slot = tt >> 6, cp = tt & 63;
            gr[u] = reinterpret_cast<const unsigned*>(yf)[(jo_s[slot] >> 1) + cp];
        }

        // phase 2: wij = h @ W2
        f32x4 acc2[2][2] = {};
        #pragma unroll
        for (int rb = 0; rb < 2; ++rb) {
            half8 a[4];
            #pragma unroll
            for (int kb = 0; kb < 4; ++kb) {
                const int e  = rb * 16 + lr;
                const int k0 = kb * 32 + lk * 8;
                a[kb] = *reinterpret_cast<const half8*>(
                    &Ash[e * 136 + (k0 ^ ((e & 7) << 3))]);
            }
            #pragma unroll
            for (int cb = 0; cb < 2; ++cb)
                #pragma unroll
                for (int kb = 0; kb < 4; ++kb)
                    acc2[rb][cb] = __builtin_amdgcn_mfma_f32_16x16x32_f16(
                        a[kb], b2fr[kb][cb], acc2[rb][cb], 0, 0, 0);
        }

        // g ds_writes into M_s (stride 138, free since top sync)
        #pragma unroll
        for (int u = 0; u < 8; ++u) {
            const int tt = u * 256 + tid;
            const int slot = tt >> 6, cp = tt & 63;
            *reinterpret_cast<unsigned*>(&M_s[slot * 138 + cp * 2]) = gr[u];
        }
        __syncthreads();               // g visible; phase-2 Ash reads done

        // per-thread: M = wv*g in place + y-side atomics (valid slots only)
        #pragma unroll
        for (int rb = 0; rb < 2; ++rb)
            #pragma unroll
            for (int cb = 0; cb < 2; ++cb) {
                const int col = wcol0 + cb * 16 + lr;
                #pragma unroll
                for (int q = 0; q < 4; ++q) {
                    const int e = rb * 16 + lk * 4 + q;
                    const float wv = (acc2[rb][cb][q] + b2c[cb]) * rc_s[e];
                    const float g  = (float)M_s[e * 138 + col];
                    M_s[e * 138 + col] = (_Float16)(wv * g);
                    if (e < cnt) {
                        const int oi = ni_s[e] - n0;
                        const float xo = (float)xown[oi * 136 + col];
                        unsafeAtomicAdd(&conv_y[(size_t)jo_s[e] + col], xo * wv);
                    }
                }
            }
        __syncthreads();

        // phase 3: accS += S @ M  (selector one-hot, K=32)
        {
            half8 as;
            int nn[8];
            #pragma unroll
            for (int j = 0; j < 8; ++j) nn[j] = ni_s[lk * 8 + j];
            const int node = n0 + lr;
            #pragma unroll
            for (int j = 0; j < 8; ++j)
                as[j] = (nn[j] == node) ? (_Float16)1.f : (_Float16)0.f;
            #pragma unroll
            for (int cb = 0; cb < 2; ++cb) {
                const int col = wcol0 + cb * 16 + lr;
                half8 bm;
                #pragma unroll
                for (int j = 0; j < 8; ++j)
                    bm[j] = M_s[(lk * 8 + j) * 138 + col];
                accS[cb] = __builtin_amdgcn_mfma_f32_16x16x32_f16(
                    as, bm, accS[cb], 0, 0, 0);
            }
        }
    }

    // conv_x rows [n0, n0+16): written once, f16 plain stores
    #pragma unroll
    for (int cb = 0; cb < 2; ++cb) {
        const int col = wcol0 + cb * 16 + lr;
        #pragma unroll
        for (int q = 0; q < 4; ++q) {
            const int n = n0 + lk * 4 + q;
            if (n < NN) conv_x[(size_t)n * NF + col] = (_Float16)accS[cb][q];
        }
    }
}

// ---------------------------------------------------------------------------
// Projection (exact grid, f16) + fused edge histogram + conv_y zero.
// ---------------------------------------------------------------------------
__global__ __launch_bounds__(256, 2)
void proj_mfma_kernel(const float* in0, const float* in1,
                      const float* __restrict__ W0, const float* __restrict__ W1p,
                      _Float16* o0, _Float16* o1,
                      float* __restrict__ conv_y,
                      const int* __restrict__ idx_i, int* __restrict__ deg,
                      int N, int E)
{
    const float* in = blockIdx.y ? in1 : in0;
    const float* W  = blockIdx.y ? W1p : W0;
    _Float16* out   = blockIdx.y ? o1 : o0;

    const int tid = threadIdx.x;
    const int l = tid & 63, w = tid >> 6;
    const int lr = l & 15, lk = l >> 4;
    const int wcol0 = w * 32;

    __shared__ _Float16 Ahi[64 * NF];

    // fused histogram slice (deg pre-zeroed by memset on same stream)
    {
        const int nb = gridDim.x * 2;
        const int bid = blockIdx.y * gridDim.x + blockIdx.x;
        for (int e = bid * 256 + tid; e < E; e += nb * 256)
            atomicAdd(&deg[idx_i[e]], 1);
    }

    half8 bfr[4][2];
    #pragma unroll
    for (int kb = 0; kb < 4; ++kb)
        #pragma unroll
        for (int cb = 0; cb < 2; ++cb) {
            const int col = wcol0 + cb * 16 + lr;
            #pragma unroll
            for (int j = 0; j < 8; ++j)
                bfr[kb][cb][j] = (_Float16)W[(size_t)(kb * 32 + lk * 8 + j) * NF + col];
        }

    const int n0 = blockIdx.x * 64;
    #pragma unroll
    for (int s = 0; s < 32; ++s) {
        const int t = s * 256 + tid;
        const int row = t >> 7, cc = t & (NF - 1);
        const float v = (n0 + row < N) ? in[(size_t)(n0 + row) * NF + cc] : 0.f;
        Ahi[row * NF + (cc ^ ((row & 7) << 3))] = (_Float16)v;
    }
    {
        const float4 z = {0.f, 0.f, 0.f, 0.f};
        const int rbase = n0 + 32 * blockIdx.y;
        #pragma unroll
        for (int s = 0; s < 4; ++s) {
            const int t = s * 256 + tid;
            const int row = rbase + (t >> 5);
            if (row < N)
                *reinterpret_cast<float4*>(&conv_y[(size_t)row * NF + (t & 31) * 4]) = z;
        }
    }
    __syncthreads();

    f32x4 acc[4][2] = {};
    #pragma unroll
    for (int rb = 0; rb < 4; ++rb) {
        half8 a[4];
        #pragma unroll
        for (int kb = 0; kb < 4; ++kb) {
            const int e  = rb * 16 + lr;
            const int k0 = kb * 32 + lk * 8;
            a[kb] = *reinterpret_cast<const half8*>(&Ahi[e * NF + (k0 ^ ((e & 7) << 3))]);
        }
        #pragma unroll
        for (int cb = 0; cb < 2; ++cb)
            #pragma unroll
            for (int kb = 0; kb < 4; ++kb)
                acc[rb][cb] = __builtin_amdgcn_mfma_f32_16x16x32_f16(
                    a[kb], bfr[kb][cb], acc[rb][cb], 0, 0, 0);
    }

    #pragma unroll
    for (int rb = 0; rb < 4; ++rb)
        #pragma unroll
        for (int cb = 0; cb < 2; ++cb) {
            const int col = wcol0 + cb * 16 + lr;
            #pragma unroll
            for (int q = 0; q < 4; ++q) {
                const int n = n0 + rb * 16 + lk * 4 + q;
                if (n < N) out[(size_t)n * NF + col] = (_Float16)acc[rb][cb][q];
            }
        }
}

// ---------------------------------------------------------------------------
// Fused output MLP (exact grid, plain f16): out = ssp(conv@W1+b1)@W2 + b2
// conv_x is f16, conv_y is fp32 (mixed, selected per branch).
// ---------------------------------------------------------------------------
__global__ __launch_bounds__(256, 2)
void out_fused_kernel(const _Float16* convx, const float* convy,
                      const float* __restrict__ W10, const float* __restrict__ W11,
                      const float* __restrict__ b10, const float* __restrict__ b11,
                      const float* __restrict__ W20, const float* __restrict__ W21,
                      const float* __restrict__ b20, const float* __restrict__ b21,
                      float* o0, float* o1, int N)
{
    const int yb = blockIdx.y;
    const float* W1 = yb ? W11 : W10;
    const float* b1 = yb ? b11 : b10;
    const float* W2 = yb ? W21 : W20;
    const float* b2 = yb ? b21 : b20;
    float* out      = yb ? o1  : o0;

    const int tid = threadIdx.x;
    const int l = tid & 63, w = tid >> 6;
    const int lr = l & 15, lk = l >> 4;
    const int wcol0 = w * 32;

    __shared__ _Float16 Ahi[64 * NF];

    half8 w1fr[4][2], w2fr[4][2];
    #pragma unroll
    for (int kb = 0; kb < 4; ++kb)
        #pragma unroll
        for (int cb = 0; cb < 2; ++cb) {
            const int col = wcol0 + cb * 16 + lr;
            #pragma unroll
            for (int j = 0; j < 8; ++j) {
                const size_t kk = (size_t)(kb * 32 + lk * 8 + j) * NF + col;
                w1fr[kb][cb][j] = (_Float16)W1[kk];
                w2fr[kb][cb][j] = (_Float16)W2[kk];
            }
        }
    const float b1c0 = b1[wcol0 + lr], b1c1 = b1[wcol0 + 16 + lr];
    const float b2c0 = b2[wcol0 + lr], b2c1 = b2[wcol0 + 16 + lr];

    const int n0 = blockIdx.x * 64;
    if (yb) {
        #pragma unroll
        for (int s = 0; s < 32; ++s) {
            const int t = s * 256 + tid;
            const int row = t >> 7, cc = t & (NF - 1);
            const float v = (n0 + row < N) ? convy[(size_t)(n0 + row) * NF + cc] : 0.f;
            Ahi[row * NF + (cc ^ ((row & 7) << 3))] = (_Float16)v;
        }
    } else {
        #pragma unroll
        for (int s = 0; s < 32; ++s) {
            const int t = s * 256 + tid;
            const int row = t >> 7, cc = t & (NF - 1);
            const _Float16 v = (n0 + row < N)
                ? convx[(size_t)(n0 + row) * NF + cc] : (_Float16)0.f;
            Ahi[row * NF + (cc ^ ((row & 7) << 3))] = v;
        }
    }
    __syncthreads();

    f32x4 acc1[4][2] = {};
    #pragma unroll
    for (int rb = 0; rb < 4; ++rb) {
        half8 a[4];
        #pragma unroll
        for (int kb = 0; kb < 4; ++kb) {
            const int e  = rb * 16 + lr;
            const int k0 = kb * 32 + lk * 8;
            a[kb] = *reinterpret_cast<const half8*>(&Ahi[e * NF + (k0 ^ ((e & 7) << 3))]);
        }
        #pragma unroll
        for (int cb = 0; cb < 2; ++cb)
            #pragma unroll
            for (int kb = 0; kb < 4; ++kb)
                acc1[rb][cb] = __builtin_amdgcn_mfma_f32_16x16x32_f16(
                    a[kb], w1fr[kb][cb], acc1[rb][cb], 0, 0, 0);
    }
    __syncthreads();

    #pragma unroll
    for (int rb = 0; rb < 4; ++rb)
        #pragma unroll
        for (int cb = 0; cb < 2; ++cb) {
            const int col = wcol0 + cb * 16 + lr;
            #pragma unroll
            for (int q = 0; q < 4; ++q) {
                const int e = rb * 16 + lk * 4 + q;
                const float hv = sspf(acc1[rb][cb][q] + (cb ? b1c1 : b1c0));
                Ahi[e * NF + (col ^ ((e & 7) << 3))] = (_Float16)hv;
            }
        }
    __syncthreads();

    f32x4 acc2[4][2] = {};
    #pragma unroll
    for (int rb = 0; rb < 4; ++rb) {
        half8 a[4];
        #pragma unroll
        for (int kb = 0; kb < 4; ++kb) {
            const int e  = rb * 16 + lr;
            const int k0 = kb * 32 + lk * 8;
            a[kb] = *reinterpret_cast<const half8*>(&Ahi[e * NF + (k0 ^ ((e & 7) << 3))]);
        }
        #pragma unroll
        for (int cb = 0; cb < 2; ++cb)
            #pragma unroll
            for (int kb = 0; kb < 4; ++kb)
                acc2[rb][cb] = __builtin_amdgcn_mfma_f32_16x16x32_f16(
                    a[kb], w2fr[kb][cb], acc2[rb][cb], 0, 0, 0);
    }

    #pragma unroll
    for (int rb = 0; rb < 4; ++rb)
        #pragma unroll
        for (int cb = 0; cb < 2; ++cb) {
            const int col = wcol0 + cb * 16 + lr;
            #pragma unroll
            for (int q = 0; q < 4; ++q) {
                const int n = n0 + rb * 16 + lk * 4 + q;
                if (n < N)
                    out[(size_t)n * NF + col] = acc2[rb][cb][q] + (cb ? b2c1 : b2c0);
            }
        }
}

extern "C" void kernel_launch(void* const* d_in, const int* in_sizes, int n_in,
                              void* d_out, int out_size, void* d_ws, size_t ws_size,
                              hipStream_t stream)
{
    const float* x    = (const float*)d_in[0];
    const float* y    = (const float*)d_in[1];
    const float* f_ij = (const float*)d_in[2];
    const float* rcut = (const float*)d_in[3];
    const int* idx_i  = (const int*)d_in[4];
    const int* idx_j  = (const int*)d_in[5];
    const float* W_in2f   = (const float*)d_in[6];
    const float* W_in2f_y = (const float*)d_in[7];
    const float* Wf1 = (const float*)d_in[8];
    const float* bf1 = (const float*)d_in[9];
    const float* Wf2 = (const float*)d_in[10];
    const float* bf2 = (const float*)d_in[11];
    const float* Wx1 = (const float*)d_in[12];
    const float* bx1 = (const float*)d_in[13];
    const float* Wx2 = (const float*)d_in[14];
    const float* bx2 = (const float*)d_in[15];
    const float* Wy1 = (const float*)d_in[16];
    const float* by1 = (const float*)d_in[17];
    const float* Wy2 = (const float*)d_in[18];
    const float* by2 = (const float*)d_in[19];

    const int N = in_sizes[0] / NF;
    const int E = in_sizes[4];
    const size_t NNF = (size_t)N * NF;

    _Float16* xf = (_Float16*)d_out;
    _Float16* yf = xf + NNF;
    float* ox = (float*)d_out;
    float* oy = ox + NNF;

    // upper half of d_out: sort scratch + sorted edge data (dead before
    // out_fused writes). Budget: 1.6 + 7.2 + 38.4 = 47.2 MB <= 51.2 MB.
    char* ub = (char*)d_out + 4 * NNF;
    int* deg   = (int*)ub;
    int* loc   = deg + N;
    int* rowp  = loc + N;
    int* cur   = rowp + N;
    int* parts = cur + N;              // 64 ints
    int* nis   = parts + 64;           // E
    int* jos   = nis + E;              // E
    float* rcs = (float*)(jos + E);    // E
    _Float16* f16s = (_Float16*)(rcs + E);   // E * 32 halves (64B-aligned)

    // ws: conv_y fp32 (atomic target) + conv_x f16 (plain stores)
    float* conv_y = (float*)d_ws;                  // [N*NF] fp32
    _Float16* conv_x = (_Float16*)(conv_y + NNF);  // [N*NF] f16

    const int NB = (N + 2047) / 2048;
    const int nodeTiles = (N + 63) / 64;
    const int nGroups = (N + 15) / 16;

    hipMemsetAsync(deg, 0, (size_t)N * sizeof(int), stream);

    proj_mfma_kernel<<<dim3(nodeTiles, 2), 256, 0, stream>>>(
        x, y, W_in2f, W_in2f_y, xf, yf, conv_y, idx_i, deg, N, E);

    scanA1_kernel<<<NB, 256, 0, stream>>>(deg, loc, parts, N);
    scanB1_kernel<<<1, 64, 0, stream>>>(parts, NB);
    scanC1_kernel<<<128, 256, 0, stream>>>(loc, parts, rowp, cur, N);
    scatter1_kernel<<<2048, 256, 0, stream>>>(idx_i, idx_j, rcut, f_ij, cur,
                                              nis, jos, rcs, f16s, E);

    edge_hybrid_kernel<<<nGroups, 256, 0, stream>>>(
        f16s, nis, jos, rcs, Wf1, bf1, Wf2, bf2, xf, yf,
        rowp, conv_x, conv_y, N, E);

    out_fused_kernel<<<dim3(nodeTiles, 2), 256, 0, stream>>>(
        conv_x, conv_y, Wx1, Wy1, bx1, by1, Wx2, Wy2, bx2, by2,
        ox, oy, N);
}